// Round 2
// baseline (1334.667 us; speedup 1.0000x reference)
//
#include <hip/hip_runtime.h>
#include <math.h>

#define N_NODES 50000
#define N_EDGES 600000
#define HID 128
#define NLAYERS 4
#define NODE_IN 16
#define EDGE_IN 8
#define LN_EPS 1e-5f
#define AST 132   // padded LDS row stride (floats) -> conflict-free A reads/writes
#define SCAN_BLOCKS ((N_NODES + 255) / 256)

// ---------------- edge_index dtype detection (int32 vs int64) ----------------
__global__ void detect_i64(const int* ei, int* flag) {
    __shared__ int nz;
    if (threadIdx.x == 0) nz = 0;
    __syncthreads();
    int acc = 0;
    for (int i = threadIdx.x; i < 1024; i += blockDim.x)
        if (ei[2 * i + 1] != 0) acc = 1;
    if (acc) atomicOr(&nz, 1);
    __syncthreads();
    if (threadIdx.x == 0) *flag = (nz == 0) ? 1 : 0;
}

__device__ __forceinline__ int edge_src(const void* ei, int f, int e) {
    if (f) return (int)((const long long*)ei)[e];
    return ((const int*)ei)[e];
}
__device__ __forceinline__ int edge_dst(const void* ei, int f, int e) {
    if (f) return (int)((const long long*)ei)[N_EDGES + e];
    return ((const int*)ei)[N_EDGES + e];
}

// ---------------- CSR build ----------------
__global__ void hist_k(const void* ei, const int* flag, int* cursor) {
    int e = blockIdx.x * blockDim.x + threadIdx.x;
    if (e >= N_EDGES) return;
    int f = *flag;
    atomicAdd(&cursor[edge_dst(ei, f, e)], 1);
}

// 3-phase scan: per-block local exclusive scan + partial totals
__global__ void scan1_k(const int* __restrict__ cursor, int* __restrict__ locex,
                        int* __restrict__ partials) {
    __shared__ int sd[256];
    int t = threadIdx.x, i = blockIdx.x * 256 + t;
    int v = (i < N_NODES) ? cursor[i] : 0;
    sd[t] = v;
    __syncthreads();
    for (int off = 1; off < 256; off <<= 1) {
        int x = (t >= off) ? sd[t - off] : 0;
        __syncthreads();
        sd[t] += x;
        __syncthreads();
    }
    if (i < N_NODES) locex[i] = sd[t] - v;
    if (t == 255) partials[blockIdx.x] = sd[255];
}

__global__ void scan2_k(int* partials) {
    __shared__ int sd[256];
    int t = threadIdx.x;
    int v = (t < SCAN_BLOCKS) ? partials[t] : 0;
    sd[t] = v;
    __syncthreads();
    for (int off = 1; off < 256; off <<= 1) {
        int x = (t >= off) ? sd[t - off] : 0;
        __syncthreads();
        sd[t] += x;
        __syncthreads();
    }
    if (t < SCAN_BLOCKS) partials[t] = sd[t] - v;  // exclusive
    if (t == 255) partials[SCAN_BLOCKS] = sd[255]; // total
}

__global__ void scan3_k(int* __restrict__ row_ptr, int* __restrict__ cursor,
                        const int* __restrict__ partials) {
    int i = blockIdx.x * 256 + threadIdx.x;
    if (i < N_NODES) {
        int r = row_ptr[i] + partials[blockIdx.x];
        row_ptr[i] = r;
        cursor[i] = r;
    }
    if (i == N_NODES) row_ptr[N_NODES] = partials[SCAN_BLOCKS];
}

__global__ void place_k(const void* ei, const int* flag, int* cursor,
                        int* sorted_src, int* sorted_eid) {
    int e = blockIdx.x * blockDim.x + threadIdx.x;
    if (e >= N_EDGES) return;
    int f = *flag;
    int s = edge_src(ei, f, e);
    int d = edge_dst(ei, f, e);
    int pos = atomicAdd(&cursor[d], 1);
    sorted_src[pos] = s;
    sorted_eid[pos] = e;
}

// ---------------- weight precompute ----------------
// M[l][k][c]  = sum_j edge_w[k][j] * ledge_w[l][j][c]            (4*8*128)
// cb[l][c]    = lnode_b[l][c] + ledge_b[l][c] + sum_j edge_b[j]*ledge_w[l][j][c]
// v[l][k]     = sum_j edge_w[k][j] * adm_w[l][j]
// cgate[l]    = sum_j edge_b[j] * adm_w[l][j] + adm_b[l]
__global__ void precompute_k(const float* __restrict__ edge_w, const float* __restrict__ edge_b,
                             const float* __restrict__ ledge_w, const float* __restrict__ ledge_b,
                             const float* __restrict__ lnode_b,
                             const float* __restrict__ adm_w, const float* __restrict__ adm_b,
                             float* __restrict__ M, float* __restrict__ cb,
                             float* __restrict__ v, float* __restrict__ cgate) {
    int t = blockIdx.x * 256 + threadIdx.x;
    if (t < 4096) {
        int l = t >> 10, k = (t >> 7) & 7, ch = t & 127;
        const float* lw = ledge_w + (size_t)l * HID * HID;
        float a = 0.f;
        for (int j = 0; j < HID; ++j) a += edge_w[k * HID + j] * lw[j * HID + ch];
        M[t] = a;
    } else if (t < 4608) {
        int u = t - 4096;
        int l = u >> 7, ch = u & 127;
        const float* lw = ledge_w + (size_t)l * HID * HID;
        float a = ledge_b[l * HID + ch] + lnode_b[l * HID + ch];
        for (int j = 0; j < HID; ++j) a += edge_b[j] * lw[j * HID + ch];
        cb[u] = a;
    } else if (t < 4640) {
        int u = t - 4608;
        int l = u >> 3, k = u & 7;
        float a = 0.f;
        for (int j = 0; j < HID; ++j) a += edge_w[k * HID + j] * adm_w[l * HID + j];
        v[u] = a;
    } else if (t < 4644) {
        int l = t - 4640;
        float a = adm_b[l];
        for (int j = 0; j < HID; ++j) a += edge_b[j] * adm_w[l * HID + j];
        cgate[l] = a;
    }
}

// ---------------- per-edge gates: y4[e] = sigmoid(edge_attr[e] . v_l + c_l) --
__global__ __launch_bounds__(256) void yorig_k(const float* __restrict__ edge_attr,
                                               const float* __restrict__ v,
                                               const float* __restrict__ cgate,
                                               float4* __restrict__ y4) {
    __shared__ float sv[36];
    if (threadIdx.x < 32) sv[threadIdx.x] = v[threadIdx.x];
    else if (threadIdx.x < 36) sv[threadIdx.x] = cgate[threadIdx.x - 32];
    __syncthreads();
    int e = blockIdx.x * 256 + threadIdx.x;
    if (e >= N_EDGES) return;
    float4 a0 = ((const float4*)edge_attr)[(size_t)e * 2];
    float4 a1 = ((const float4*)edge_attr)[(size_t)e * 2 + 1];
    float pr[NLAYERS];
#pragma unroll
    for (int l = 0; l < NLAYERS; ++l) {
        const float* vl = &sv[l * 8];
        float p = sv[32 + l];
        p += a0.x * vl[0] + a0.y * vl[1] + a0.z * vl[2] + a0.w * vl[3];
        p += a1.x * vl[4] + a1.y * vl[5] + a1.z * vl[6] + a1.w * vl[7];
        pr[l] = 1.0f / (1.0f + expf(-p));
    }
    y4[e] = make_float4(pr[0], pr[1], pr[2], pr[3]);
}

// ---------------- per-node edge stats for ALL layers ----------------
// agg8[l][n][8] = sum_{e->n} y_l[e]*edge_attr[e];  sy[l][n] = sum y_l
// also scatter y into layer-major sorted order for the gather passes.
__global__ __launch_bounds__(256) void node_stats_k(
    const int* __restrict__ row_ptr, const int* __restrict__ sorted_eid,
    const float* __restrict__ edge_attr, const float4* __restrict__ y4,
    float* __restrict__ agg8, float* __restrict__ sy_arr,
    float* __restrict__ y_sorted) {
    int n = blockIdx.x * 256 + threadIdx.x;
    if (n >= N_NODES) return;
    int ps = row_ptr[n], pe = row_ptr[n + 1];
    float a8[NLAYERS][8];
    float sy[NLAYERS];
#pragma unroll
    for (int l = 0; l < NLAYERS; ++l) {
        sy[l] = 0.f;
#pragma unroll
        for (int k = 0; k < 8; ++k) a8[l][k] = 0.f;
    }
    for (int p = ps; p < pe; ++p) {
        int eid = sorted_eid[p];
        float4 e0 = ((const float4*)edge_attr)[(size_t)eid * 2];
        float4 e1 = ((const float4*)edge_attr)[(size_t)eid * 2 + 1];
        float4 y = y4[eid];
        float yl[NLAYERS] = {y.x, y.y, y.z, y.w};
#pragma unroll
        for (int l = 0; l < NLAYERS; ++l) {
            float yy = yl[l];
            y_sorted[(size_t)l * N_EDGES + p] = yy;
            sy[l] += yy;
            a8[l][0] += yy * e0.x; a8[l][1] += yy * e0.y;
            a8[l][2] += yy * e0.z; a8[l][3] += yy * e0.w;
            a8[l][4] += yy * e1.x; a8[l][5] += yy * e1.y;
            a8[l][6] += yy * e1.z; a8[l][7] += yy * e1.w;
        }
    }
#pragma unroll
    for (int l = 0; l < NLAYERS; ++l) {
        size_t base = ((size_t)l * N_NODES + n) * 2;
        ((float4*)agg8)[base]     = make_float4(a8[l][0], a8[l][1], a8[l][2], a8[l][3]);
        ((float4*)agg8)[base + 1] = make_float4(a8[l][4], a8[l][5], a8[l][6], a8[l][7]);
        sy_arr[(size_t)l * N_NODES + n] = sy[l];
    }
}

// ---------------- h0 = x @ node_w + node_b ----------------
__global__ void node_encode_k(const float* __restrict__ x, const float* __restrict__ nw,
                              const float* __restrict__ nb, float* __restrict__ h) {
    int idx = blockIdx.x * 256 + threadIdx.x;
    if (idx >= N_NODES * HID) return;
    int n = idx >> 7, c = idx & 127;
    float acc = nb[c];
#pragma unroll
    for (int k = 0; k < NODE_IN; ++k) acc += x[n * NODE_IN + k] * nw[k * HID + c];
    h[idx] = acc;
}

// ---------------- fused layer: gather + GEMM + LN + residual ----------------
// block: 64 nodes. Phase 1: 4 waves gather gh rows (sum y*h_in[src]) into LDS A.
// Phase 2: acc init from agg8@M + sy*cb. Phase 3: A@lnode_w (Wt staged 32 rows
// at a time). Phase 4: LayerNorm + relu + residual, h_out = h_in + relu(xn).
__global__ __launch_bounds__(256) void layer_k(
    const float* __restrict__ h_in, float* __restrict__ h_out,
    const int* __restrict__ row_ptr, const int* __restrict__ sorted_src,
    const float* __restrict__ y_l, const float* __restrict__ W,
    const float* __restrict__ M_l, const float* __restrict__ cb_l,
    const float* __restrict__ agg8_l, const float* __restrict__ sy_l,
    const float* __restrict__ gm, const float* __restrict__ bt) {
    __shared__ float A[64 * AST];     // 33792 B
    __shared__ float Wt[32 * HID];    // 16384 B
    const int tid = threadIdx.x;
    const int n0 = blockIdx.x * 64;
    const int wid = tid >> 6, lane = tid & 63;

    // ---- phase 1: gather
#pragma unroll 1
    for (int jj = 0; jj < 16; ++jj) {
        int row = wid * 16 + jj;
        int n = n0 + row;
        float a0 = 0.f, a1 = 0.f;
        if (n < N_NODES) {
            int ps = row_ptr[n], pe = row_ptr[n + 1];
            int p = ps;
            for (; p + 1 < pe; p += 2) {
                float y0 = y_l[p], y1 = y_l[p + 1];
                int s0 = sorted_src[p], s1 = sorted_src[p + 1];
                const float* hp0 = h_in + (size_t)s0 * HID;
                const float* hp1 = h_in + (size_t)s1 * HID;
                a0 += y0 * hp0[lane];
                a1 += y0 * hp0[64 + lane];
                a0 += y1 * hp1[lane];
                a1 += y1 * hp1[64 + lane];
            }
            if (p < pe) {
                float y0 = y_l[p];
                const float* hp0 = h_in + (size_t)sorted_src[p] * HID;
                a0 += y0 * hp0[lane];
                a1 += y0 * hp0[64 + lane];
            }
        }
        A[row * AST + lane] = a0;
        A[row * AST + 64 + lane] = a1;
    }

    // ---- phase 2: acc init = sy*cb + agg8 @ M
    const int tm = tid >> 4, tn = tid & 15;
    float acc[4][8];
    float cbl[8];
#pragma unroll
    for (int c = 0; c < 8; ++c) cbl[c] = cb_l[tn * 8 + c];
#pragma unroll
    for (int j = 0; j < 4; ++j) {
        int n = n0 + tm * 4 + j;
        float syv = 0.f;
        float a8[8];
#pragma unroll
        for (int k = 0; k < 8; ++k) a8[k] = 0.f;
        if (n < N_NODES) {
            syv = sy_l[n];
            float4 t0 = ((const float4*)agg8_l)[(size_t)n * 2];
            float4 t1 = ((const float4*)agg8_l)[(size_t)n * 2 + 1];
            a8[0] = t0.x; a8[1] = t0.y; a8[2] = t0.z; a8[3] = t0.w;
            a8[4] = t1.x; a8[5] = t1.y; a8[6] = t1.z; a8[7] = t1.w;
        }
#pragma unroll
        for (int c = 0; c < 8; ++c) acc[j][c] = syv * cbl[c];
#pragma unroll
        for (int k = 0; k < 8; ++k) {
            float ak = a8[k];
            float4 m0 = *(const float4*)&M_l[k * HID + tn * 8];
            float4 m1 = *(const float4*)&M_l[k * HID + tn * 8 + 4];
            acc[j][0] += ak * m0.x; acc[j][1] += ak * m0.y;
            acc[j][2] += ak * m0.z; acc[j][3] += ak * m0.w;
            acc[j][4] += ak * m1.x; acc[j][5] += ak * m1.y;
            acc[j][6] += ak * m1.z; acc[j][7] += ak * m1.w;
        }
    }

    // ---- phase 3: GEMM  acc += A @ W   (K staged in 4 chunks of 32)
#pragma unroll
    for (int kc = 0; kc < 4; ++kc) {
        __syncthreads();
#pragma unroll
        for (int i = 0; i < 4; ++i) {
            int f4 = tid + i * 256;
            ((float4*)Wt)[f4] = ((const float4*)W)[kc * 1024 + f4];
        }
        __syncthreads();
#pragma unroll 8
        for (int k = 0; k < 32; k += 2) {
            float2 av[4];
#pragma unroll
            for (int j = 0; j < 4; ++j)
                av[j] = *(const float2*)&A[(tm * 4 + j) * AST + kc * 32 + k];
            float4 w00 = *(const float4*)&Wt[k * HID + tn * 8];
            float4 w01 = *(const float4*)&Wt[k * HID + tn * 8 + 4];
            float4 w10 = *(const float4*)&Wt[(k + 1) * HID + tn * 8];
            float4 w11 = *(const float4*)&Wt[(k + 1) * HID + tn * 8 + 4];
#pragma unroll
            for (int j = 0; j < 4; ++j) {
                acc[j][0] += av[j].x * w00.x; acc[j][1] += av[j].x * w00.y;
                acc[j][2] += av[j].x * w00.z; acc[j][3] += av[j].x * w00.w;
                acc[j][4] += av[j].x * w01.x; acc[j][5] += av[j].x * w01.y;
                acc[j][6] += av[j].x * w01.z; acc[j][7] += av[j].x * w01.w;
                acc[j][0] += av[j].y * w10.x; acc[j][1] += av[j].y * w10.y;
                acc[j][2] += av[j].y * w10.z; acc[j][3] += av[j].y * w10.w;
                acc[j][4] += av[j].y * w11.x; acc[j][5] += av[j].y * w11.y;
                acc[j][6] += av[j].y * w11.z; acc[j][7] += av[j].y * w11.w;
            }
        }
    }

    // ---- phase 4: LayerNorm + relu + residual
    float4 ga0 = ((const float4*)gm)[tn * 2], ga1 = ((const float4*)gm)[tn * 2 + 1];
    float4 be0 = ((const float4*)bt)[tn * 2], be1 = ((const float4*)bt)[tn * 2 + 1];
#pragma unroll
    for (int j = 0; j < 4; ++j) {
        float s = acc[j][0] + acc[j][1] + acc[j][2] + acc[j][3] +
                  acc[j][4] + acc[j][5] + acc[j][6] + acc[j][7];
        s += __shfl_xor(s, 1, 64); s += __shfl_xor(s, 2, 64);
        s += __shfl_xor(s, 4, 64); s += __shfl_xor(s, 8, 64);
        float mean = s * (1.0f / HID);
        float d[8];
        float vs = 0.f;
#pragma unroll
        for (int c = 0; c < 8; ++c) { d[c] = acc[j][c] - mean; vs += d[c] * d[c]; }
        vs += __shfl_xor(vs, 1, 64); vs += __shfl_xor(vs, 2, 64);
        vs += __shfl_xor(vs, 4, 64); vs += __shfl_xor(vs, 8, 64);
        float rstd = rsqrtf(vs * (1.0f / HID) + LN_EPS);
        int n = n0 + tm * 4 + j;
        if (n < N_NODES) {
            float4 h0 = ((const float4*)h_in)[(size_t)n * 32 + tn * 2];
            float4 h1 = ((const float4*)h_in)[(size_t)n * 32 + tn * 2 + 1];
            h0.x += fmaxf(d[0] * rstd * ga0.x + be0.x, 0.f);
            h0.y += fmaxf(d[1] * rstd * ga0.y + be0.y, 0.f);
            h0.z += fmaxf(d[2] * rstd * ga0.z + be0.z, 0.f);
            h0.w += fmaxf(d[3] * rstd * ga0.w + be0.w, 0.f);
            h1.x += fmaxf(d[4] * rstd * ga1.x + be1.x, 0.f);
            h1.y += fmaxf(d[5] * rstd * ga1.y + be1.y, 0.f);
            h1.z += fmaxf(d[6] * rstd * ga1.z + be1.z, 0.f);
            h1.w += fmaxf(d[7] * rstd * ga1.w + be1.w, 0.f);
            ((float4*)h_out)[(size_t)n * 32 + tn * 2] = h0;
            ((float4*)h_out)[(size_t)n * 32 + tn * 2 + 1] = h1;
        }
    }
}

extern "C" void kernel_launch(void* const* d_in, const int* in_sizes, int n_in,
                              void* d_out, int out_size, void* d_ws, size_t ws_size,
                              hipStream_t stream) {
    const float* x         = (const float*)d_in[0];
    const void*  ei        = d_in[1];
    const float* edge_attr = (const float*)d_in[2];
    const float* node_w    = (const float*)d_in[3];
    const float* node_b    = (const float*)d_in[4];
    const float* edge_w    = (const float*)d_in[5];
    const float* edge_b    = (const float*)d_in[6];
    const float* lnode_w   = (const float*)d_in[7];
    const float* lnode_b   = (const float*)d_in[8];
    const float* ledge_w   = (const float*)d_in[9];
    const float* ledge_b   = (const float*)d_in[10];
    const float* adm_w     = (const float*)d_in[11];
    const float* adm_b     = (const float*)d_in[12];
    const float* gamma     = (const float*)d_in[13];
    const float* beta      = (const float*)d_in[14];
    float* h = (float*)d_out;

    char* wp = (char*)d_ws;
    auto alloc = [&](size_t bytes) -> void* {
        void* p = (void*)wp;
        wp += (bytes + 255) & ~(size_t)255;
        return p;
    };
    int*    flag       = (int*)alloc(256);
    int*    cursor     = (int*)alloc(sizeof(int) * N_NODES);
    int*    row_ptr    = (int*)alloc(sizeof(int) * (N_NODES + 1));
    int*    partials   = (int*)alloc(sizeof(int) * (SCAN_BLOCKS + 1));
    int*    sorted_src = (int*)alloc(sizeof(int) * N_EDGES);
    int*    sorted_eid = (int*)alloc(sizeof(int) * N_EDGES);
    float4* y4         = (float4*)alloc(sizeof(float4) * N_EDGES);
    float*  y_sorted   = (float*)alloc(sizeof(float) * NLAYERS * N_EDGES);
    float*  agg8       = (float*)alloc(sizeof(float) * NLAYERS * N_NODES * 8);
    float*  sy_arr     = (float*)alloc(sizeof(float) * NLAYERS * N_NODES);
    float*  Mw         = (float*)alloc(sizeof(float) * NLAYERS * 8 * HID);
    float*  cbw        = (float*)alloc(sizeof(float) * NLAYERS * HID);
    float*  vw         = (float*)alloc(sizeof(float) * NLAYERS * 8);
    float*  cgate      = (float*)alloc(sizeof(float) * NLAYERS);
    float*  hbuf       = (float*)alloc(sizeof(float) * (size_t)N_NODES * HID);
    (void)ws_size; (void)in_sizes; (void)n_in; (void)out_size;

    hipMemsetAsync(cursor, 0, sizeof(int) * N_NODES, stream);
    detect_i64<<<1, 256, 0, stream>>>((const int*)ei, flag);
    hist_k<<<(N_EDGES + 255) / 256, 256, 0, stream>>>(ei, flag, cursor);
    scan1_k<<<SCAN_BLOCKS, 256, 0, stream>>>(cursor, row_ptr, partials);
    scan2_k<<<1, 256, 0, stream>>>(partials);
    scan3_k<<<SCAN_BLOCKS, 256, 0, stream>>>(row_ptr, cursor, partials);
    place_k<<<(N_EDGES + 255) / 256, 256, 0, stream>>>(ei, flag, cursor, sorted_src, sorted_eid);
    precompute_k<<<19, 256, 0, stream>>>(edge_w, edge_b, ledge_w, ledge_b, lnode_b,
                                         adm_w, adm_b, Mw, cbw, vw, cgate);
    yorig_k<<<(N_EDGES + 255) / 256, 256, 0, stream>>>(edge_attr, vw, cgate, y4);
    node_stats_k<<<SCAN_BLOCKS, 256, 0, stream>>>(row_ptr, sorted_eid, edge_attr, y4,
                                                  agg8, sy_arr, y_sorted);
    node_encode_k<<<(N_NODES * HID + 255) / 256, 256, 0, stream>>>(x, node_w, node_b, h);

    float* hin = h;
    float* hout = hbuf;
    for (int l = 0; l < NLAYERS; ++l) {
        layer_k<<<(N_NODES + 63) / 64, 256, 0, stream>>>(
            hin, hout, row_ptr, sorted_src,
            y_sorted + (size_t)l * N_EDGES, lnode_w + (size_t)l * HID * HID,
            Mw + (size_t)l * 8 * HID, cbw + (size_t)l * HID,
            agg8 + (size_t)l * N_NODES * 8, sy_arr + (size_t)l * N_NODES,
            gamma + (size_t)l * HID, beta + (size_t)l * HID);
        float* t = hin; hin = hout; hout = t;
    }
    // NLAYERS is even -> final result lands back in d_out
}

// Round 3
// 615.510 us; speedup vs baseline: 2.1684x; 2.1684x over previous
//
#include <hip/hip_runtime.h>
#include <math.h>

#define N_NODES 50000
#define N_EDGES 600000
#define HID 128
#define NLAYERS 4
#define NODE_IN 16
#define EDGE_IN 8
#define LN_EPS 1e-5f
#define SCAN_BLOCKS ((N_NODES + 255) / 256)

// ---------------- edge_index dtype detection (int32 vs int64) ----------------
__global__ void detect_i64(const int* ei, int* flag) {
    __shared__ int nz;
    if (threadIdx.x == 0) nz = 0;
    __syncthreads();
    int acc = 0;
    for (int i = threadIdx.x; i < 1024; i += blockDim.x)
        if (ei[2 * i + 1] != 0) acc = 1;
    if (acc) atomicOr(&nz, 1);
    __syncthreads();
    if (threadIdx.x == 0) *flag = (nz == 0) ? 1 : 0;
}

__device__ __forceinline__ int edge_src(const void* ei, int f, int e) {
    if (f) return (int)((const long long*)ei)[e];
    return ((const int*)ei)[e];
}
__device__ __forceinline__ int edge_dst(const void* ei, int f, int e) {
    if (f) return (int)((const long long*)ei)[N_EDGES + e];
    return ((const int*)ei)[N_EDGES + e];
}

// ---------------- CSR build ----------------
__global__ void hist_k(const void* ei, const int* flag, int* cursor) {
    int e = blockIdx.x * blockDim.x + threadIdx.x;
    if (e >= N_EDGES) return;
    int f = *flag;
    atomicAdd(&cursor[edge_dst(ei, f, e)], 1);
}

__global__ void scan1_k(const int* __restrict__ cursor, int* __restrict__ locex,
                        int* __restrict__ partials) {
    __shared__ int sd[256];
    int t = threadIdx.x, i = blockIdx.x * 256 + t;
    int v = (i < N_NODES) ? cursor[i] : 0;
    sd[t] = v;
    __syncthreads();
    for (int off = 1; off < 256; off <<= 1) {
        int x = (t >= off) ? sd[t - off] : 0;
        __syncthreads();
        sd[t] += x;
        __syncthreads();
    }
    if (i < N_NODES) locex[i] = sd[t] - v;
    if (t == 255) partials[blockIdx.x] = sd[255];
}

__global__ void scan2_k(int* partials) {
    __shared__ int sd[256];
    int t = threadIdx.x;
    int v = (t < SCAN_BLOCKS) ? partials[t] : 0;
    sd[t] = v;
    __syncthreads();
    for (int off = 1; off < 256; off <<= 1) {
        int x = (t >= off) ? sd[t - off] : 0;
        __syncthreads();
        sd[t] += x;
        __syncthreads();
    }
    if (t < SCAN_BLOCKS) partials[t] = sd[t] - v;
    if (t == 255) partials[SCAN_BLOCKS] = sd[255];
}

__global__ void scan3_k(int* __restrict__ row_ptr, int* __restrict__ cursor,
                        const int* __restrict__ partials) {
    int i = blockIdx.x * 256 + threadIdx.x;
    if (i < N_NODES) {
        int r = row_ptr[i] + partials[blockIdx.x];
        row_ptr[i] = r;
        cursor[i] = r;
    }
    if (i == N_NODES) row_ptr[N_NODES] = partials[SCAN_BLOCKS];
}

__global__ void place_k(const void* ei, const int* flag, int* cursor,
                        int* sorted_src, int* sorted_eid) {
    int e = blockIdx.x * blockDim.x + threadIdx.x;
    if (e >= N_EDGES) return;
    int f = *flag;
    int s = edge_src(ei, f, e);
    int d = edge_dst(ei, f, e);
    int pos = atomicAdd(&cursor[d], 1);
    sorted_src[pos] = s;
    sorted_eid[pos] = e;
}

// ---------------- weight precompute ----------------
__global__ void precompute_k(const float* __restrict__ edge_w, const float* __restrict__ edge_b,
                             const float* __restrict__ ledge_w, const float* __restrict__ ledge_b,
                             const float* __restrict__ lnode_b,
                             const float* __restrict__ adm_w, const float* __restrict__ adm_b,
                             float* __restrict__ M, float* __restrict__ cb,
                             float* __restrict__ v, float* __restrict__ cgate) {
    int t = blockIdx.x * 256 + threadIdx.x;
    if (t < 4096) {
        int l = t >> 10, k = (t >> 7) & 7, ch = t & 127;
        const float* lw = ledge_w + (size_t)l * HID * HID;
        float a = 0.f;
        for (int j = 0; j < HID; ++j) a += edge_w[k * HID + j] * lw[j * HID + ch];
        M[t] = a;
    } else if (t < 4608) {
        int u = t - 4096;
        int l = u >> 7, ch = u & 127;
        const float* lw = ledge_w + (size_t)l * HID * HID;
        float a = ledge_b[l * HID + ch] + lnode_b[l * HID + ch];
        for (int j = 0; j < HID; ++j) a += edge_b[j] * lw[j * HID + ch];
        cb[u] = a;
    } else if (t < 4640) {
        int u = t - 4608;
        int l = u >> 3, k = u & 7;
        float a = 0.f;
        for (int j = 0; j < HID; ++j) a += edge_w[k * HID + j] * adm_w[l * HID + j];
        v[u] = a;
    } else if (t < 4644) {
        int l = t - 4640;
        float a = adm_b[l];
        for (int j = 0; j < HID; ++j) a += edge_b[j] * adm_w[l * HID + j];
        cgate[l] = a;
    }
}

// ---------------- per-edge gates (original edge order) ----------------
__global__ __launch_bounds__(256) void yorig_k(const float* __restrict__ edge_attr,
                                               const float* __restrict__ v,
                                               const float* __restrict__ cgate,
                                               float4* __restrict__ y4) {
    __shared__ float sv[36];
    if (threadIdx.x < 32) sv[threadIdx.x] = v[threadIdx.x];
    else if (threadIdx.x < 36) sv[threadIdx.x] = cgate[threadIdx.x - 32];
    __syncthreads();
    int e = blockIdx.x * 256 + threadIdx.x;
    if (e >= N_EDGES) return;
    float4 a0 = ((const float4*)edge_attr)[(size_t)e * 2];
    float4 a1 = ((const float4*)edge_attr)[(size_t)e * 2 + 1];
    float pr[NLAYERS];
#pragma unroll
    for (int l = 0; l < NLAYERS; ++l) {
        const float* vl = &sv[l * 8];
        float p = sv[32 + l];
        p += a0.x * vl[0] + a0.y * vl[1] + a0.z * vl[2] + a0.w * vl[3];
        p += a1.x * vl[4] + a1.y * vl[5] + a1.z * vl[6] + a1.w * vl[7];
        pr[l] = 1.0f / (1.0f + expf(-p));
    }
    y4[e] = make_float4(pr[0], pr[1], pr[2], pr[3]);
}

// ---------------- per-node edge stats, 8 nodes/wave, 8 lanes/node ----------
__global__ __launch_bounds__(256) void node_stats_k(
    const int* __restrict__ row_ptr, const int* __restrict__ sorted_eid,
    const float* __restrict__ edge_attr, const float4* __restrict__ y4,
    float* __restrict__ agg8, float* __restrict__ sy_arr,
    float* __restrict__ y_sorted) {
    int lane = threadIdx.x & 63;
    int gw = (blockIdx.x * 256 + threadIdx.x) >> 6;
    int g = lane >> 3, k = lane & 7;
    int nslots = (gridDim.x * 256) >> 3;   // total node slots per pass
    for (int base = gw * 8; base < N_NODES; base += nslots) {
        int n = base + g;
        bool valid = (n < N_NODES);
        int ps = valid ? row_ptr[n] : 0;
        int pe = valid ? row_ptr[n + 1] : 0;
        float a0 = 0.f, a1 = 0.f, a2 = 0.f, a3 = 0.f;
        float s0 = 0.f, s1 = 0.f, s2 = 0.f, s3 = 0.f;
        for (int p = ps; p < pe; ++p) {
            int eid = sorted_eid[p];
            float ea = edge_attr[(size_t)eid * EDGE_IN + k];
            float4 y = y4[eid];
            float yk = (k == 0) ? y.x : (k == 1) ? y.y : (k == 2) ? y.z : y.w;
            if (k < 4) y_sorted[(size_t)k * N_EDGES + p] = yk;
            a0 += y.x * ea; a1 += y.y * ea; a2 += y.z * ea; a3 += y.w * ea;
            s0 += y.x; s1 += y.y; s2 += y.z; s3 += y.w;
        }
        if (valid) {
            agg8[((size_t)0 * N_NODES + n) * 8 + k] = a0;
            agg8[((size_t)1 * N_NODES + n) * 8 + k] = a1;
            agg8[((size_t)2 * N_NODES + n) * 8 + k] = a2;
            agg8[((size_t)3 * N_NODES + n) * 8 + k] = a3;
            if (k == 0) {
                sy_arr[(size_t)0 * N_NODES + n] = s0;
                sy_arr[(size_t)1 * N_NODES + n] = s1;
                sy_arr[(size_t)2 * N_NODES + n] = s2;
                sy_arr[(size_t)3 * N_NODES + n] = s3;
            }
        }
    }
}

// ---------------- h0 = x @ node_w + node_b ----------------
__global__ void node_encode_k(const float* __restrict__ x, const float* __restrict__ nw,
                              const float* __restrict__ nb, float* __restrict__ h) {
    int idx = blockIdx.x * 256 + threadIdx.x;
    if (idx >= N_NODES * HID) return;
    int n = idx >> 7, c = idx & 127;
    float acc = nb[c];
#pragma unroll
    for (int k = 0; k < NODE_IN; ++k) acc += x[n * NODE_IN + k] * nw[k * HID + c];
    h[idx] = acc;
}

// ---------------- gather: gh[n] = sum_{e->n} y_l[e] * h_in[src[e]] ----------
// wave-per-node, grid-stride; 4-edge unroll -> 8 independent 256B loads in flight
__global__ __launch_bounds__(256) void gather_k(
    const int* __restrict__ row_ptr, const int* __restrict__ sorted_src,
    const float* __restrict__ y_l, const float* __restrict__ h_in,
    float* __restrict__ gh) {
    int lane = threadIdx.x & 63;
    int gw = (blockIdx.x * 256 + threadIdx.x) >> 6;
    int nw = (gridDim.x * 256) >> 6;
    for (int n = gw; n < N_NODES; n += nw) {
        int ps = row_ptr[n], pe = row_ptr[n + 1];
        float a0 = 0.f, a1 = 0.f;
        int p = ps;
        for (; p + 3 < pe; p += 4) {
            int s0 = sorted_src[p], s1 = sorted_src[p + 1];
            int s2 = sorted_src[p + 2], s3 = sorted_src[p + 3];
            float y0 = y_l[p], y1 = y_l[p + 1], y2 = y_l[p + 2], y3 = y_l[p + 3];
            const float* hp0 = h_in + (size_t)s0 * HID;
            const float* hp1 = h_in + (size_t)s1 * HID;
            const float* hp2 = h_in + (size_t)s2 * HID;
            const float* hp3 = h_in + (size_t)s3 * HID;
            float v00 = hp0[lane], v01 = hp0[64 + lane];
            float v10 = hp1[lane], v11 = hp1[64 + lane];
            float v20 = hp2[lane], v21 = hp2[64 + lane];
            float v30 = hp3[lane], v31 = hp3[64 + lane];
            a0 += y0 * v00; a1 += y0 * v01;
            a0 += y1 * v10; a1 += y1 * v11;
            a0 += y2 * v20; a1 += y2 * v21;
            a0 += y3 * v30; a1 += y3 * v31;
        }
        for (; p < pe; ++p) {
            int s = sorted_src[p];
            float y = y_l[p];
            const float* hp = h_in + (size_t)s * HID;
            a0 += y * hp[lane];
            a1 += y * hp[64 + lane];
        }
        gh[(size_t)n * HID + lane] = a0;
        gh[(size_t)n * HID + 64 + lane] = a1;
    }
}

// ---------------- GEMM + LN + residual ----------------
// 64 nodes/block; A (=gh) read directly from global (16-way lane broadcast,
// L1-served); only W staged in LDS (16 KB) -> occupancy not LDS-limited.
__global__ __launch_bounds__(256) void gemm_ln_k(
    const float* __restrict__ gh, const float* __restrict__ W,
    const float* __restrict__ M_l, const float* __restrict__ cb_l,
    const float* __restrict__ agg8_l, const float* __restrict__ sy_l,
    const float* __restrict__ gm, const float* __restrict__ bt,
    const float* __restrict__ h_in, float* __restrict__ h_out) {
    __shared__ float Wt[32 * HID];
    const int tid = threadIdx.x;
    const int n0 = blockIdx.x * 64;
    const int tm = tid >> 4, tn = tid & 15;

    // acc init = sy*cb + agg8 @ M
    float acc[4][8];
    float cbl[8];
#pragma unroll
    for (int c = 0; c < 8; ++c) cbl[c] = cb_l[tn * 8 + c];
#pragma unroll
    for (int j = 0; j < 4; ++j) {
        int n = n0 + tm * 4 + j;
        float syv = 0.f;
        float a8[8];
#pragma unroll
        for (int k = 0; k < 8; ++k) a8[k] = 0.f;
        if (n < N_NODES) {
            syv = sy_l[n];
            float4 t0 = ((const float4*)agg8_l)[(size_t)n * 2];
            float4 t1 = ((const float4*)agg8_l)[(size_t)n * 2 + 1];
            a8[0] = t0.x; a8[1] = t0.y; a8[2] = t0.z; a8[3] = t0.w;
            a8[4] = t1.x; a8[5] = t1.y; a8[6] = t1.z; a8[7] = t1.w;
        }
#pragma unroll
        for (int c = 0; c < 8; ++c) acc[j][c] = syv * cbl[c];
#pragma unroll
        for (int k = 0; k < 8; ++k) {
            float ak = a8[k];
            float4 m0 = *(const float4*)&M_l[k * HID + tn * 8];
            float4 m1 = *(const float4*)&M_l[k * HID + tn * 8 + 4];
            acc[j][0] += ak * m0.x; acc[j][1] += ak * m0.y;
            acc[j][2] += ak * m0.z; acc[j][3] += ak * m0.w;
            acc[j][4] += ak * m1.x; acc[j][5] += ak * m1.y;
            acc[j][6] += ak * m1.z; acc[j][7] += ak * m1.w;
        }
    }

    int row[4];
#pragma unroll
    for (int j = 0; j < 4; ++j) {
        int n = n0 + tm * 4 + j;
        row[j] = (n < N_NODES) ? n : (N_NODES - 1);   // clamp; result discarded
    }

    // GEMM: acc += gh @ W, K staged in 4 chunks of 32
#pragma unroll
    for (int kc = 0; kc < 4; ++kc) {
        __syncthreads();
#pragma unroll
        for (int i = 0; i < 4; ++i) {
            int f4 = tid + i * 256;
            ((float4*)Wt)[f4] = ((const float4*)W)[kc * 1024 + f4];
        }
        __syncthreads();
#pragma unroll 8
        for (int k = 0; k < 32; k += 2) {
            float2 av[4];
#pragma unroll
            for (int j = 0; j < 4; ++j)
                av[j] = *(const float2*)&gh[(size_t)row[j] * HID + kc * 32 + k];
            float4 w00 = *(const float4*)&Wt[k * HID + tn * 8];
            float4 w01 = *(const float4*)&Wt[k * HID + tn * 8 + 4];
            float4 w10 = *(const float4*)&Wt[(k + 1) * HID + tn * 8];
            float4 w11 = *(const float4*)&Wt[(k + 1) * HID + tn * 8 + 4];
#pragma unroll
            for (int j = 0; j < 4; ++j) {
                acc[j][0] += av[j].x * w00.x; acc[j][1] += av[j].x * w00.y;
                acc[j][2] += av[j].x * w00.z; acc[j][3] += av[j].x * w00.w;
                acc[j][4] += av[j].x * w01.x; acc[j][5] += av[j].x * w01.y;
                acc[j][6] += av[j].x * w01.z; acc[j][7] += av[j].x * w01.w;
                acc[j][0] += av[j].y * w10.x; acc[j][1] += av[j].y * w10.y;
                acc[j][2] += av[j].y * w10.z; acc[j][3] += av[j].y * w10.w;
                acc[j][4] += av[j].y * w11.x; acc[j][5] += av[j].y * w11.y;
                acc[j][6] += av[j].y * w11.z; acc[j][7] += av[j].y * w11.w;
            }
        }
    }

    // LayerNorm + relu + residual
    float4 ga0 = ((const float4*)gm)[tn * 2], ga1 = ((const float4*)gm)[tn * 2 + 1];
    float4 be0 = ((const float4*)bt)[tn * 2], be1 = ((const float4*)bt)[tn * 2 + 1];
#pragma unroll
    for (int j = 0; j < 4; ++j) {
        float s = acc[j][0] + acc[j][1] + acc[j][2] + acc[j][3] +
                  acc[j][4] + acc[j][5] + acc[j][6] + acc[j][7];
        s += __shfl_xor(s, 1, 64); s += __shfl_xor(s, 2, 64);
        s += __shfl_xor(s, 4, 64); s += __shfl_xor(s, 8, 64);
        float mean = s * (1.0f / HID);
        float d[8];
        float vs = 0.f;
#pragma unroll
        for (int c = 0; c < 8; ++c) { d[c] = acc[j][c] - mean; vs += d[c] * d[c]; }
        vs += __shfl_xor(vs, 1, 64); vs += __shfl_xor(vs, 2, 64);
        vs += __shfl_xor(vs, 4, 64); vs += __shfl_xor(vs, 8, 64);
        float rstd = rsqrtf(vs * (1.0f / HID) + LN_EPS);
        int n = n0 + tm * 4 + j;
        if (n < N_NODES) {
            float4 h0 = ((const float4*)h_in)[(size_t)n * 32 + tn * 2];
            float4 h1 = ((const float4*)h_in)[(size_t)n * 32 + tn * 2 + 1];
            h0.x += fmaxf(d[0] * rstd * ga0.x + be0.x, 0.f);
            h0.y += fmaxf(d[1] * rstd * ga0.y + be0.y, 0.f);
            h0.z += fmaxf(d[2] * rstd * ga0.z + be0.z, 0.f);
            h0.w += fmaxf(d[3] * rstd * ga0.w + be0.w, 0.f);
            h1.x += fmaxf(d[4] * rstd * ga1.x + be1.x, 0.f);
            h1.y += fmaxf(d[5] * rstd * ga1.y + be1.y, 0.f);
            h1.z += fmaxf(d[6] * rstd * ga1.z + be1.z, 0.f);
            h1.w += fmaxf(d[7] * rstd * ga1.w + be1.w, 0.f);
            ((float4*)h_out)[(size_t)n * 32 + tn * 2] = h0;
            ((float4*)h_out)[(size_t)n * 32 + tn * 2 + 1] = h1;
        }
    }
}

extern "C" void kernel_launch(void* const* d_in, const int* in_sizes, int n_in,
                              void* d_out, int out_size, void* d_ws, size_t ws_size,
                              hipStream_t stream) {
    const float* x         = (const float*)d_in[0];
    const void*  ei        = d_in[1];
    const float* edge_attr = (const float*)d_in[2];
    const float* node_w    = (const float*)d_in[3];
    const float* node_b    = (const float*)d_in[4];
    const float* edge_w    = (const float*)d_in[5];
    const float* edge_b    = (const float*)d_in[6];
    const float* lnode_w   = (const float*)d_in[7];
    const float* lnode_b   = (const float*)d_in[8];
    const float* ledge_w   = (const float*)d_in[9];
    const float* ledge_b   = (const float*)d_in[10];
    const float* adm_w     = (const float*)d_in[11];
    const float* adm_b     = (const float*)d_in[12];
    const float* gamma     = (const float*)d_in[13];
    const float* beta      = (const float*)d_in[14];
    float* h = (float*)d_out;

    char* wp = (char*)d_ws;
    auto alloc = [&](size_t bytes) -> void* {
        void* p = (void*)wp;
        wp += (bytes + 255) & ~(size_t)255;
        return p;
    };
    int*    flag       = (int*)alloc(256);
    int*    cursor     = (int*)alloc(sizeof(int) * N_NODES);
    int*    row_ptr    = (int*)alloc(sizeof(int) * (N_NODES + 1));
    int*    partials   = (int*)alloc(sizeof(int) * (SCAN_BLOCKS + 1));
    int*    sorted_src = (int*)alloc(sizeof(int) * N_EDGES);
    int*    sorted_eid = (int*)alloc(sizeof(int) * N_EDGES);
    float4* y4         = (float4*)alloc(sizeof(float4) * N_EDGES);
    float*  y_sorted   = (float*)alloc(sizeof(float) * NLAYERS * N_EDGES);
    float*  agg8       = (float*)alloc(sizeof(float) * NLAYERS * N_NODES * 8);
    float*  sy_arr     = (float*)alloc(sizeof(float) * NLAYERS * N_NODES);
    float*  Mw         = (float*)alloc(sizeof(float) * NLAYERS * 8 * HID);
    float*  cbw        = (float*)alloc(sizeof(float) * NLAYERS * HID);
    float*  vw         = (float*)alloc(sizeof(float) * NLAYERS * 8);
    float*  cgate      = (float*)alloc(sizeof(float) * NLAYERS);
    float*  hbuf       = (float*)alloc(sizeof(float) * (size_t)N_NODES * HID);
    float*  gh         = (float*)alloc(sizeof(float) * (size_t)N_NODES * HID);
    (void)ws_size; (void)in_sizes; (void)n_in; (void)out_size;

    hipMemsetAsync(cursor, 0, sizeof(int) * N_NODES, stream);
    detect_i64<<<1, 256, 0, stream>>>((const int*)ei, flag);
    hist_k<<<(N_EDGES + 255) / 256, 256, 0, stream>>>(ei, flag, cursor);
    scan1_k<<<SCAN_BLOCKS, 256, 0, stream>>>(cursor, row_ptr, partials);
    scan2_k<<<1, 256, 0, stream>>>(partials);
    scan3_k<<<SCAN_BLOCKS, 256, 0, stream>>>(row_ptr, cursor, partials);
    place_k<<<(N_EDGES + 255) / 256, 256, 0, stream>>>(ei, flag, cursor, sorted_src, sorted_eid);
    precompute_k<<<19, 256, 0, stream>>>(edge_w, edge_b, ledge_w, ledge_b, lnode_b,
                                         adm_w, adm_b, Mw, cbw, vw, cgate);
    yorig_k<<<(N_EDGES + 255) / 256, 256, 0, stream>>>(edge_attr, vw, cgate, y4);
    node_stats_k<<<512, 256, 0, stream>>>(row_ptr, sorted_eid, edge_attr, y4,
                                          agg8, sy_arr, y_sorted);
    node_encode_k<<<(N_NODES * HID + 255) / 256, 256, 0, stream>>>(x, node_w, node_b, h);

    float* hin = h;
    float* hout = hbuf;
    for (int l = 0; l < NLAYERS; ++l) {
        gather_k<<<2048, 256, 0, stream>>>(
            row_ptr, sorted_src, y_sorted + (size_t)l * N_EDGES, hin, gh);
        gemm_ln_k<<<(N_NODES + 63) / 64, 256, 0, stream>>>(
            gh, lnode_w + (size_t)l * HID * HID,
            Mw + (size_t)l * 8 * HID, cbw + (size_t)l * HID,
            agg8 + (size_t)l * N_NODES * 8, sy_arr + (size_t)l * N_NODES,
            gamma + (size_t)l * HID, beta + (size_t)l * HID, hin, hout);
        float* t = hin; hin = hout; hout = t;
    }
    // NLAYERS even -> final result lands in d_out
}

// Round 4
// 459.035 us; speedup vs baseline: 2.9075x; 1.3409x over previous
//
#include <hip/hip_runtime.h>
#include <math.h>

#define N_NODES 50000
#define N_EDGES 600000
#define HID 128
#define NLAYERS 4
#define NODE_IN 16
#define EDGE_IN 8
#define LN_EPS 1e-5f
#define SCAN_BLOCKS ((N_NODES + 255) / 256)

typedef short bf16x8 __attribute__((ext_vector_type(8)));
typedef float f32x4 __attribute__((ext_vector_type(4)));

__device__ __forceinline__ float b2f(unsigned short u) {
    union { unsigned int i; float f; } v; v.i = ((unsigned int)u) << 16; return v.f;
}
__device__ __forceinline__ unsigned short f2b(float x) {
    union { float f; unsigned int i; } v; v.f = x;
    unsigned int b = v.i + 0x7FFFu + ((v.i >> 16) & 1u);
    return (unsigned short)(b >> 16);
}

// ---------------- edge_index dtype detection (int32 vs int64) ----------------
__global__ void detect_i64(const int* ei, int* flag) {
    __shared__ int nz;
    if (threadIdx.x == 0) nz = 0;
    __syncthreads();
    int acc = 0;
    for (int i = threadIdx.x; i < 1024; i += blockDim.x)
        if (ei[2 * i + 1] != 0) acc = 1;
    if (acc) atomicOr(&nz, 1);
    __syncthreads();
    if (threadIdx.x == 0) *flag = (nz == 0) ? 1 : 0;
}

__device__ __forceinline__ int edge_src(const void* ei, int f, int e) {
    if (f) return (int)((const long long*)ei)[e];
    return ((const int*)ei)[e];
}
__device__ __forceinline__ int edge_dst(const void* ei, int f, int e) {
    if (f) return (int)((const long long*)ei)[N_EDGES + e];
    return ((const int*)ei)[N_EDGES + e];
}

// ---------------- CSR build ----------------
__global__ void hist_k(const void* ei, const int* flag, int* cursor) {
    int e = blockIdx.x * blockDim.x + threadIdx.x;
    if (e >= N_EDGES) return;
    int f = *flag;
    atomicAdd(&cursor[edge_dst(ei, f, e)], 1);
}

__global__ void scan1_k(const int* __restrict__ cursor, int* __restrict__ locex,
                        int* __restrict__ partials) {
    __shared__ int sd[256];
    int t = threadIdx.x, i = blockIdx.x * 256 + t;
    int v = (i < N_NODES) ? cursor[i] : 0;
    sd[t] = v;
    __syncthreads();
    for (int off = 1; off < 256; off <<= 1) {
        int x = (t >= off) ? sd[t - off] : 0;
        __syncthreads();
        sd[t] += x;
        __syncthreads();
    }
    if (i < N_NODES) locex[i] = sd[t] - v;
    if (t == 255) partials[blockIdx.x] = sd[255];
}

__global__ void scan2_k(int* partials) {
    __shared__ int sd[256];
    int t = threadIdx.x;
    int v = (t < SCAN_BLOCKS) ? partials[t] : 0;
    sd[t] = v;
    __syncthreads();
    for (int off = 1; off < 256; off <<= 1) {
        int x = (t >= off) ? sd[t - off] : 0;
        __syncthreads();
        sd[t] += x;
        __syncthreads();
    }
    if (t < SCAN_BLOCKS) partials[t] = sd[t] - v;
    if (t == 255) partials[SCAN_BLOCKS] = sd[255];
}

__global__ void scan3_k(int* __restrict__ row_ptr, int* __restrict__ cursor,
                        const int* __restrict__ partials) {
    int i = blockIdx.x * 256 + threadIdx.x;
    if (i < N_NODES) {
        int r = row_ptr[i] + partials[blockIdx.x];
        row_ptr[i] = r;
        cursor[i] = r;
    }
    if (i == N_NODES) row_ptr[N_NODES] = partials[SCAN_BLOCKS];
}

__global__ void place_k(const void* ei, const int* flag, int* cursor,
                        int* sorted_src, int* sorted_eid) {
    int e = blockIdx.x * blockDim.x + threadIdx.x;
    if (e >= N_EDGES) return;
    int f = *flag;
    int s = edge_src(ei, f, e);
    int d = edge_dst(ei, f, e);
    int pos = atomicAdd(&cursor[d], 1);
    sorted_src[pos] = s;
    sorted_eid[pos] = e;
}

// ---------------- weight precompute (f32 epilogue constants) ----------------
__global__ void precompute_k(const float* __restrict__ edge_w, const float* __restrict__ edge_b,
                             const float* __restrict__ ledge_w, const float* __restrict__ ledge_b,
                             const float* __restrict__ lnode_b,
                             const float* __restrict__ adm_w, const float* __restrict__ adm_b,
                             float* __restrict__ M, float* __restrict__ cb,
                             float* __restrict__ v, float* __restrict__ cgate) {
    int t = blockIdx.x * 256 + threadIdx.x;
    if (t < 4096) {
        int l = t >> 10, k = (t >> 7) & 7, ch = t & 127;
        const float* lw = ledge_w + (size_t)l * HID * HID;
        float a = 0.f;
        for (int j = 0; j < HID; ++j) a += edge_w[k * HID + j] * lw[j * HID + ch];
        M[t] = a;
    } else if (t < 4608) {
        int u = t - 4096;
        int l = u >> 7, ch = u & 127;
        const float* lw = ledge_w + (size_t)l * HID * HID;
        float a = ledge_b[l * HID + ch] + lnode_b[l * HID + ch];
        for (int j = 0; j < HID; ++j) a += edge_b[j] * lw[j * HID + ch];
        cb[u] = a;
    } else if (t < 4640) {
        int u = t - 4608;
        int l = u >> 3, k = u & 7;
        float a = 0.f;
        for (int j = 0; j < HID; ++j) a += edge_w[k * HID + j] * adm_w[l * HID + j];
        v[u] = a;
    } else if (t < 4644) {
        int l = t - 4640;
        float a = adm_b[l];
        for (int j = 0; j < HID; ++j) a += edge_b[j] * adm_w[l * HID + j];
        cgate[l] = a;
    }
}

// ---- W^T bf16: Wt16[l][n][k] = bf16(lnode_w[l][k][n]) (B-operand, k-contig) --
__global__ void convertw_k(const float* __restrict__ lnode_w, unsigned short* __restrict__ Wt16) {
    int idx = blockIdx.x * 256 + threadIdx.x;
    if (idx >= NLAYERS * HID * HID) return;
    int l = idx >> 14, r = idx & 16383, n = r >> 7, k = r & 127;
    Wt16[idx] = f2b(lnode_w[(size_t)l * HID * HID + k * HID + n]);
}

// ---------------- per-edge gates (original edge order) ----------------
__global__ __launch_bounds__(256) void yorig_k(const float* __restrict__ edge_attr,
                                               const float* __restrict__ v,
                                               const float* __restrict__ cgate,
                                               float4* __restrict__ y4) {
    __shared__ float sv[36];
    if (threadIdx.x < 32) sv[threadIdx.x] = v[threadIdx.x];
    else if (threadIdx.x < 36) sv[threadIdx.x] = cgate[threadIdx.x - 32];
    __syncthreads();
    int e = blockIdx.x * 256 + threadIdx.x;
    if (e >= N_EDGES) return;
    float4 a0 = ((const float4*)edge_attr)[(size_t)e * 2];
    float4 a1 = ((const float4*)edge_attr)[(size_t)e * 2 + 1];
    float pr[NLAYERS];
#pragma unroll
    for (int l = 0; l < NLAYERS; ++l) {
        const float* vl = &sv[l * 8];
        float p = sv[32 + l];
        p += a0.x * vl[0] + a0.y * vl[1] + a0.z * vl[2] + a0.w * vl[3];
        p += a1.x * vl[4] + a1.y * vl[5] + a1.z * vl[6] + a1.w * vl[7];
        pr[l] = 1.0f / (1.0f + expf(-p));
    }
    y4[e] = make_float4(pr[0], pr[1], pr[2], pr[3]);
}

// ---------------- per-node edge stats, 8 nodes/wave, 8 lanes/node ----------
__global__ __launch_bounds__(256) void node_stats_k(
    const int* __restrict__ row_ptr, const int* __restrict__ sorted_eid,
    const float* __restrict__ edge_attr, const float4* __restrict__ y4,
    float* __restrict__ agg8, float* __restrict__ sy_arr,
    float* __restrict__ y_sorted) {
    int lane = threadIdx.x & 63;
    int gw = (blockIdx.x * 256 + threadIdx.x) >> 6;
    int g = lane >> 3, k = lane & 7;
    int nslots = (gridDim.x * 256) >> 3;
    for (int base = gw * 8; base < N_NODES; base += nslots) {
        int n = base + g;
        bool valid = (n < N_NODES);
        int ps = valid ? row_ptr[n] : 0;
        int pe = valid ? row_ptr[n + 1] : 0;
        float a0 = 0.f, a1 = 0.f, a2 = 0.f, a3 = 0.f;
        float s0 = 0.f, s1 = 0.f, s2 = 0.f, s3 = 0.f;
        for (int p = ps; p < pe; ++p) {
            int eid = sorted_eid[p];
            float ea = edge_attr[(size_t)eid * EDGE_IN + k];
            float4 y = y4[eid];
            float yk = (k == 0) ? y.x : (k == 1) ? y.y : (k == 2) ? y.z : y.w;
            if (k < 4) y_sorted[(size_t)k * N_EDGES + p] = yk;
            a0 += y.x * ea; a1 += y.y * ea; a2 += y.z * ea; a3 += y.w * ea;
            s0 += y.x; s1 += y.y; s2 += y.z; s3 += y.w;
        }
        if (valid) {
            agg8[((size_t)0 * N_NODES + n) * 8 + k] = a0;
            agg8[((size_t)1 * N_NODES + n) * 8 + k] = a1;
            agg8[((size_t)2 * N_NODES + n) * 8 + k] = a2;
            agg8[((size_t)3 * N_NODES + n) * 8 + k] = a3;
            if (k == 0) {
                sy_arr[(size_t)0 * N_NODES + n] = s0;
                sy_arr[(size_t)1 * N_NODES + n] = s1;
                sy_arr[(size_t)2 * N_NODES + n] = s2;
                sy_arr[(size_t)3 * N_NODES + n] = s3;
            }
        }
    }
}

// ---------------- h0 = x @ node_w + node_b  (f32 + bf16 copies) --------------
__global__ void node_encode_k(const float* __restrict__ x, const float* __restrict__ nw,
                              const float* __restrict__ nb, float* __restrict__ h,
                              unsigned short* __restrict__ h16) {
    int idx = blockIdx.x * 256 + threadIdx.x;
    if (idx >= N_NODES * HID) return;
    int n = idx >> 7, c = idx & 127;
    float acc = nb[c];
#pragma unroll
    for (int k = 0; k < NODE_IN; ++k) acc += x[n * NODE_IN + k] * nw[k * HID + c];
    h[idx] = acc;
    h16[idx] = f2b(acc);
}

// ---------------- gather (bf16 h): gh16[n] = bf16(sum y_l[e]*h16[src[e]]) ----
__global__ __launch_bounds__(256) void gather16_k(
    const int* __restrict__ row_ptr, const int* __restrict__ sorted_src,
    const float* __restrict__ y_l, const unsigned short* __restrict__ h16,
    unsigned int* __restrict__ gh16) {
    int lane = threadIdx.x & 63;
    int gw = (blockIdx.x * 256 + threadIdx.x) >> 6;
    int nw = (gridDim.x * 256) >> 6;
    for (int n = gw; n < N_NODES; n += nw) {
        int ps = row_ptr[n], pe = row_ptr[n + 1];
        float a0 = 0.f, a1 = 0.f;
        int p = ps;
        for (; p + 3 < pe; p += 4) {
            int s0 = sorted_src[p], s1 = sorted_src[p + 1];
            int s2 = sorted_src[p + 2], s3 = sorted_src[p + 3];
            float y0 = y_l[p], y1 = y_l[p + 1], y2 = y_l[p + 2], y3 = y_l[p + 3];
            unsigned int v0 = *(const unsigned int*)(h16 + (size_t)s0 * HID + lane * 2);
            unsigned int v1 = *(const unsigned int*)(h16 + (size_t)s1 * HID + lane * 2);
            unsigned int v2 = *(const unsigned int*)(h16 + (size_t)s2 * HID + lane * 2);
            unsigned int v3 = *(const unsigned int*)(h16 + (size_t)s3 * HID + lane * 2);
            a0 += y0 * b2f((unsigned short)v0); a1 += y0 * b2f((unsigned short)(v0 >> 16));
            a0 += y1 * b2f((unsigned short)v1); a1 += y1 * b2f((unsigned short)(v1 >> 16));
            a0 += y2 * b2f((unsigned short)v2); a1 += y2 * b2f((unsigned short)(v2 >> 16));
            a0 += y3 * b2f((unsigned short)v3); a1 += y3 * b2f((unsigned short)(v3 >> 16));
        }
        for (; p < pe; ++p) {
            float y = y_l[p];
            unsigned int v = *(const unsigned int*)(h16 + (size_t)sorted_src[p] * HID + lane * 2);
            a0 += y * b2f((unsigned short)v);
            a1 += y * b2f((unsigned short)(v >> 16));
        }
        gh16[(size_t)n * 64 + lane] = ((unsigned int)f2b(a1) << 16) | f2b(a0);
    }
}

// ---------------- MFMA GEMM + epilogue (init + LN + relu + residual) ---------
// 4 waves/block, wave w owns nodes [b*64+16w, +16), all 128 ch.
// A frag: gh16 row=lane&15, k=8*(lane>>4)+j. B frag: Wt16 col=lane&15 (n-major).
// D: col=lane&15, row=4*(lane>>4)+reg (m89-verified).
__global__ __launch_bounds__(256) void mfma_ln_k(
    const unsigned short* __restrict__ gh16, const unsigned short* __restrict__ Wt16,
    const float* __restrict__ M_l, const float* __restrict__ cb_l,
    const float* __restrict__ agg8_l, const float* __restrict__ sy_l,
    const float* __restrict__ gm, const float* __restrict__ bt,
    const float* __restrict__ h_in, float* __restrict__ h_out,
    unsigned short* __restrict__ h16_out) {
    const int tid = threadIdx.x;
    const int w = tid >> 6, lane = tid & 63;
    const int g = lane >> 4, c = lane & 15;
    const int nbase = blockIdx.x * 64 + w * 16;

    // A fragments (reused across all 8 column tiles)
    int arow = nbase + c;
    int arowc = (arow < N_NODES) ? arow : (N_NODES - 1);
    bf16x8 afrag[4];
#pragma unroll
    for (int kc = 0; kc < 4; ++kc)
        afrag[kc] = *(const bf16x8*)(gh16 + (size_t)arowc * HID + kc * 32 + g * 8);

    f32x4 acc[8];
#pragma unroll
    for (int cf = 0; cf < 8; ++cf) acc[cf] = (f32x4){0.f, 0.f, 0.f, 0.f};
#pragma unroll
    for (int cf = 0; cf < 8; ++cf) {
        const unsigned short* wp = Wt16 + (size_t)(cf * 16 + c) * HID + g * 8;
#pragma unroll
        for (int kc = 0; kc < 4; ++kc) {
            bf16x8 bfrag = *(const bf16x8*)(wp + kc * 32);
            acc[cf] = __builtin_amdgcn_mfma_f32_16x16x32_bf16(afrag[kc], bfrag, acc[cf], 0, 0, 0);
        }
    }

    // epilogue init: acc += sy*cb + agg8 @ M   (rows r -> node nbase+4g+r)
    float sy_v[4];
    float a8v[4][8];
#pragma unroll
    for (int r = 0; r < 4; ++r) {
        int node = nbase + 4 * g + r;
        int nc = (node < N_NODES) ? node : (N_NODES - 1);
        sy_v[r] = sy_l[nc];
        float4 t0 = ((const float4*)agg8_l)[(size_t)nc * 2];
        float4 t1 = ((const float4*)agg8_l)[(size_t)nc * 2 + 1];
        a8v[r][0] = t0.x; a8v[r][1] = t0.y; a8v[r][2] = t0.z; a8v[r][3] = t0.w;
        a8v[r][4] = t1.x; a8v[r][5] = t1.y; a8v[r][6] = t1.z; a8v[r][7] = t1.w;
    }
#pragma unroll
    for (int cf = 0; cf < 8; ++cf) {
        int ch = cf * 16 + c;
        float cbv = cb_l[ch];
        float mv[8];
#pragma unroll
        for (int k = 0; k < 8; ++k) mv[k] = M_l[k * HID + ch];
#pragma unroll
        for (int r = 0; r < 4; ++r) {
            float t = sy_v[r] * cbv;
#pragma unroll
            for (int k = 0; k < 8; ++k) t += a8v[r][k] * mv[k];
            acc[cf][r] += t;
        }
    }

    // gamma/beta per channel
    float gav[8], bev[8];
#pragma unroll
    for (int cf = 0; cf < 8; ++cf) {
        gav[cf] = gm[cf * 16 + c];
        bev[cf] = bt[cf * 16 + c];
    }

    // LayerNorm per row + relu + residual + store (f32 & bf16)
#pragma unroll
    for (int r = 0; r < 4; ++r) {
        float s = 0.f;
#pragma unroll
        for (int cf = 0; cf < 8; ++cf) s += acc[cf][r];
        s += __shfl_xor(s, 1, 64); s += __shfl_xor(s, 2, 64);
        s += __shfl_xor(s, 4, 64); s += __shfl_xor(s, 8, 64);
        float mean = s * (1.0f / HID);
        float vs = 0.f;
        float d[8];
#pragma unroll
        for (int cf = 0; cf < 8; ++cf) { d[cf] = acc[cf][r] - mean; vs += d[cf] * d[cf]; }
        vs += __shfl_xor(vs, 1, 64); vs += __shfl_xor(vs, 2, 64);
        vs += __shfl_xor(vs, 4, 64); vs += __shfl_xor(vs, 8, 64);
        float rstd = rsqrtf(vs * (1.0f / HID) + LN_EPS);
        int node = nbase + 4 * g + r;
        if (node < N_NODES) {
#pragma unroll
            for (int cf = 0; cf < 8; ++cf) {
                int ch = cf * 16 + c;
                float o = h_in[(size_t)node * HID + ch] +
                          fmaxf(d[cf] * rstd * gav[cf] + bev[cf], 0.f);
                h_out[(size_t)node * HID + ch] = o;
                h16_out[(size_t)node * HID + ch] = f2b(o);
            }
        }
    }
}

extern "C" void kernel_launch(void* const* d_in, const int* in_sizes, int n_in,
                              void* d_out, int out_size, void* d_ws, size_t ws_size,
                              hipStream_t stream) {
    const float* x         = (const float*)d_in[0];
    const void*  ei        = d_in[1];
    const float* edge_attr = (const float*)d_in[2];
    const float* node_w    = (const float*)d_in[3];
    const float* node_b    = (const float*)d_in[4];
    const float* edge_w    = (const float*)d_in[5];
    const float* edge_b    = (const float*)d_in[6];
    const float* lnode_w   = (const float*)d_in[7];
    const float* lnode_b   = (const float*)d_in[8];
    const float* ledge_w   = (const float*)d_in[9];
    const float* ledge_b   = (const float*)d_in[10];
    const float* adm_w     = (const float*)d_in[11];
    const float* adm_b     = (const float*)d_in[12];
    const float* gamma     = (const float*)d_in[13];
    const float* beta      = (const float*)d_in[14];
    float* h = (float*)d_out;

    char* wp = (char*)d_ws;
    auto alloc = [&](size_t bytes) -> void* {
        void* p = (void*)wp;
        wp += (bytes + 255) & ~(size_t)255;
        return p;
    };
    int*            flag       = (int*)alloc(256);
    int*            cursor     = (int*)alloc(sizeof(int) * N_NODES);
    int*            row_ptr    = (int*)alloc(sizeof(int) * (N_NODES + 1));
    int*            partials   = (int*)alloc(sizeof(int) * (SCAN_BLOCKS + 1));
    int*            sorted_src = (int*)alloc(sizeof(int) * N_EDGES);
    int*            sorted_eid = (int*)alloc(sizeof(int) * N_EDGES);
    float4*         y4         = (float4*)alloc(sizeof(float4) * N_EDGES);
    float*          y_sorted   = (float*)alloc(sizeof(float) * NLAYERS * N_EDGES);
    float*          agg8       = (float*)alloc(sizeof(float) * NLAYERS * N_NODES * 8);
    float*          sy_arr     = (float*)alloc(sizeof(float) * NLAYERS * N_NODES);
    float*          Mw         = (float*)alloc(sizeof(float) * NLAYERS * 8 * HID);
    float*          cbw        = (float*)alloc(sizeof(float) * NLAYERS * HID);
    float*          vw         = (float*)alloc(sizeof(float) * NLAYERS * 8);
    float*          cgate      = (float*)alloc(sizeof(float) * NLAYERS);
    float*          hbuf       = (float*)alloc(sizeof(float) * (size_t)N_NODES * HID);
    unsigned short* h16        = (unsigned short*)alloc(sizeof(short) * (size_t)N_NODES * HID);
    unsigned short* gh16       = (unsigned short*)alloc(sizeof(short) * (size_t)N_NODES * HID);
    unsigned short* Wt16       = (unsigned short*)alloc(sizeof(short) * NLAYERS * HID * HID);
    (void)ws_size; (void)in_sizes; (void)n_in; (void)out_size;

    hipMemsetAsync(cursor, 0, sizeof(int) * N_NODES, stream);
    detect_i64<<<1, 256, 0, stream>>>((const int*)ei, flag);
    hist_k<<<(N_EDGES + 255) / 256, 256, 0, stream>>>(ei, flag, cursor);
    scan1_k<<<SCAN_BLOCKS, 256, 0, stream>>>(cursor, row_ptr, partials);
    scan2_k<<<1, 256, 0, stream>>>(partials);
    scan3_k<<<SCAN_BLOCKS, 256, 0, stream>>>(row_ptr, cursor, partials);
    place_k<<<(N_EDGES + 255) / 256, 256, 0, stream>>>(ei, flag, cursor, sorted_src, sorted_eid);
    precompute_k<<<19, 256, 0, stream>>>(edge_w, edge_b, ledge_w, ledge_b, lnode_b,
                                         adm_w, adm_b, Mw, cbw, vw, cgate);
    convertw_k<<<(NLAYERS * HID * HID + 255) / 256, 256, 0, stream>>>(lnode_w, Wt16);
    yorig_k<<<(N_EDGES + 255) / 256, 256, 0, stream>>>(edge_attr, vw, cgate, y4);
    node_stats_k<<<512, 256, 0, stream>>>(row_ptr, sorted_eid, edge_attr, y4,
                                          agg8, sy_arr, y_sorted);
    node_encode_k<<<(N_NODES * HID + 255) / 256, 256, 0, stream>>>(x, node_w, node_b, h, h16);

    float* hin = h;
    float* hout = hbuf;
    for (int l = 0; l < NLAYERS; ++l) {
        gather16_k<<<2048, 256, 0, stream>>>(
            row_ptr, sorted_src, y_sorted + (size_t)l * N_EDGES, h16, (unsigned int*)gh16);
        mfma_ln_k<<<(N_NODES + 63) / 64, 256, 0, stream>>>(
            gh16, Wt16 + (size_t)l * HID * HID,
            Mw + (size_t)l * 8 * HID, cbw + (size_t)l * HID,
            agg8 + (size_t)l * N_NODES * 8, sy_arr + (size_t)l * N_NODES,
            gamma + (size_t)l * HID, beta + (size_t)l * HID,
            hin, hout, h16);
        float* t = hin; hin = hout; hout = t;
    }
    // NLAYERS even -> final f32 result lands in d_out
}

// Round 5
// 421.467 us; speedup vs baseline: 3.1667x; 1.0891x over previous
//
#include <hip/hip_runtime.h>
#include <math.h>

#define N_NODES 50000
#define N_EDGES 600000
#define HID 128
#define NLAYERS 4
#define NODE_IN 16
#define EDGE_IN 8
#define LN_EPS 1e-5f
#define SCAN_BLOCKS ((N_NODES + 255) / 256)

typedef short bf16x8 __attribute__((ext_vector_type(8)));
typedef float f32x4 __attribute__((ext_vector_type(4)));

__device__ __forceinline__ float b2f(unsigned short u) {
    union { unsigned int i; float f; } v; v.i = ((unsigned int)u) << 16; return v.f;
}
__device__ __forceinline__ unsigned short f2b(float x) {
    union { float f; unsigned int i; } v; v.f = x;
    unsigned int b = v.i + 0x7FFFu + ((v.i >> 16) & 1u);
    return (unsigned short)(b >> 16);
}

// ---------------- edge_index dtype detection (int32 vs int64) ----------------
__global__ void detect_i64(const int* ei, int* flag) {
    __shared__ int nz;
    if (threadIdx.x == 0) nz = 0;
    __syncthreads();
    int acc = 0;
    for (int i = threadIdx.x; i < 1024; i += blockDim.x)
        if (ei[2 * i + 1] != 0) acc = 1;
    if (acc) atomicOr(&nz, 1);
    __syncthreads();
    if (threadIdx.x == 0) *flag = (nz == 0) ? 1 : 0;
}

__device__ __forceinline__ int edge_src(const void* ei, int f, int e) {
    if (f) return (int)((const long long*)ei)[e];
    return ((const int*)ei)[e];
}
__device__ __forceinline__ int edge_dst(const void* ei, int f, int e) {
    if (f) return (int)((const long long*)ei)[N_EDGES + e];
    return ((const int*)ei)[N_EDGES + e];
}

// ---------------- CSR build ----------------
__global__ void hist_k(const void* ei, const int* flag, int* cursor) {
    int e = blockIdx.x * blockDim.x + threadIdx.x;
    if (e >= N_EDGES) return;
    int f = *flag;
    atomicAdd(&cursor[edge_dst(ei, f, e)], 1);
}

__global__ void scan1_k(const int* __restrict__ cursor, int* __restrict__ locex,
                        int* __restrict__ partials) {
    __shared__ int sd[256];
    int t = threadIdx.x, i = blockIdx.x * 256 + t;
    int v = (i < N_NODES) ? cursor[i] : 0;
    sd[t] = v;
    __syncthreads();
    for (int off = 1; off < 256; off <<= 1) {
        int x = (t >= off) ? sd[t - off] : 0;
        __syncthreads();
        sd[t] += x;
        __syncthreads();
    }
    if (i < N_NODES) locex[i] = sd[t] - v;
    if (t == 255) partials[blockIdx.x] = sd[255];
}

__global__ void scan2_k(int* partials) {
    __shared__ int sd[256];
    int t = threadIdx.x;
    int v = (t < SCAN_BLOCKS) ? partials[t] : 0;
    sd[t] = v;
    __syncthreads();
    for (int off = 1; off < 256; off <<= 1) {
        int x = (t >= off) ? sd[t - off] : 0;
        __syncthreads();
        sd[t] += x;
        __syncthreads();
    }
    if (t < SCAN_BLOCKS) partials[t] = sd[t] - v;
    if (t == 255) partials[SCAN_BLOCKS] = sd[255];
}

__global__ void scan3_k(int* __restrict__ row_ptr, int* __restrict__ cursor,
                        const int* __restrict__ partials) {
    int i = blockIdx.x * 256 + threadIdx.x;
    if (i < N_NODES) {
        int r = row_ptr[i] + partials[blockIdx.x];
        row_ptr[i] = r;
        cursor[i] = r;
    }
    if (i == N_NODES) row_ptr[N_NODES] = partials[SCAN_BLOCKS];
}

__global__ void place_k(const void* ei, const int* flag, int* cursor,
                        int* sorted_src, int* sorted_eid) {
    int e = blockIdx.x * blockDim.x + threadIdx.x;
    if (e >= N_EDGES) return;
    int f = *flag;
    int s = edge_src(ei, f, e);
    int d = edge_dst(ei, f, e);
    int pos = atomicAdd(&cursor[d], 1);
    sorted_src[pos] = s;
    sorted_eid[pos] = e;
}

// ---------------- weight precompute (f32 epilogue constants) ----------------
__global__ void precompute_k(const float* __restrict__ edge_w, const float* __restrict__ edge_b,
                             const float* __restrict__ ledge_w, const float* __restrict__ ledge_b,
                             const float* __restrict__ lnode_b,
                             const float* __restrict__ adm_w, const float* __restrict__ adm_b,
                             float* __restrict__ M, float* __restrict__ cb,
                             float* __restrict__ v, float* __restrict__ cgate) {
    int t = blockIdx.x * 256 + threadIdx.x;
    if (t < 4096) {
        int l = t >> 10, k = (t >> 7) & 7, ch = t & 127;
        const float* lw = ledge_w + (size_t)l * HID * HID;
        float a = 0.f;
        for (int j = 0; j < HID; ++j) a += edge_w[k * HID + j] * lw[j * HID + ch];
        M[t] = a;
    } else if (t < 4608) {
        int u = t - 4096;
        int l = u >> 7, ch = u & 127;
        const float* lw = ledge_w + (size_t)l * HID * HID;
        float a = ledge_b[l * HID + ch] + lnode_b[l * HID + ch];
        for (int j = 0; j < HID; ++j) a += edge_b[j] * lw[j * HID + ch];
        cb[u] = a;
    } else if (t < 4640) {
        int u = t - 4608;
        int l = u >> 3, k = u & 7;
        float a = 0.f;
        for (int j = 0; j < HID; ++j) a += edge_w[k * HID + j] * adm_w[l * HID + j];
        v[u] = a;
    } else if (t < 4644) {
        int l = t - 4640;
        float a = adm_b[l];
        for (int j = 0; j < HID; ++j) a += edge_b[j] * adm_w[l * HID + j];
        cgate[l] = a;
    }
}

// ---- W^T bf16: Wt16[l][n][k] = bf16(lnode_w[l][k][n]) (B-operand, k-contig) --
__global__ void convertw_k(const float* __restrict__ lnode_w, unsigned short* __restrict__ Wt16) {
    int idx = blockIdx.x * 256 + threadIdx.x;
    if (idx >= NLAYERS * HID * HID) return;
    int l = idx >> 14, r = idx & 16383, n = r >> 7, k = r & 127;
    Wt16[idx] = f2b(lnode_w[(size_t)l * HID * HID + k * HID + n]);
}

// ---------------- per-edge gates (original edge order) ----------------
__global__ __launch_bounds__(256) void yorig_k(const float* __restrict__ edge_attr,
                                               const float* __restrict__ v,
                                               const float* __restrict__ cgate,
                                               float4* __restrict__ y4) {
    __shared__ float sv[36];
    if (threadIdx.x < 32) sv[threadIdx.x] = v[threadIdx.x];
    else if (threadIdx.x < 36) sv[threadIdx.x] = cgate[threadIdx.x - 32];
    __syncthreads();
    int e = blockIdx.x * 256 + threadIdx.x;
    if (e >= N_EDGES) return;
    float4 a0 = ((const float4*)edge_attr)[(size_t)e * 2];
    float4 a1 = ((const float4*)edge_attr)[(size_t)e * 2 + 1];
    float pr[NLAYERS];
#pragma unroll
    for (int l = 0; l < NLAYERS; ++l) {
        const float* vl = &sv[l * 8];
        float p = sv[32 + l];
        p += a0.x * vl[0] + a0.y * vl[1] + a0.z * vl[2] + a0.w * vl[3];
        p += a1.x * vl[4] + a1.y * vl[5] + a1.z * vl[6] + a1.w * vl[7];
        pr[l] = 1.0f / (1.0f + expf(-p));
    }
    y4[e] = make_float4(pr[0], pr[1], pr[2], pr[3]);
}

// ---------------- per-node edge stats: ONE WAVE PER NODE ----------------
// lane = 8*es + k: 8 edge-slots x 8 channels. Wave covers 8 edges of its node
// per iteration (independent loads -> pipelined); shfl_xor reduce over es.
__global__ __launch_bounds__(256) void node_stats_k(
    const int* __restrict__ row_ptr, const int* __restrict__ sorted_eid,
    const float* __restrict__ edge_attr, const float4* __restrict__ y4,
    float* __restrict__ agg8, float* __restrict__ sy_arr,
    float* __restrict__ y_sorted) {
    int lane = threadIdx.x & 63;
    int n = (blockIdx.x * 256 + threadIdx.x) >> 6;
    if (n >= N_NODES) return;
    int es = lane >> 3, k = lane & 7;
    int ps = row_ptr[n], pe = row_ptr[n + 1];
    float a0 = 0.f, a1 = 0.f, a2 = 0.f, a3 = 0.f;
    float s0 = 0.f, s1 = 0.f, s2 = 0.f, s3 = 0.f;
    for (int p = ps + es; p < pe; p += 8) {
        int eid = sorted_eid[p];
        float ea = edge_attr[(size_t)eid * EDGE_IN + k];
        float4 y = y4[eid];
        float yk = (k == 0) ? y.x : (k == 1) ? y.y : (k == 2) ? y.z : y.w;
        if (k < 4) y_sorted[(size_t)k * N_EDGES + p] = yk;
        a0 += y.x * ea; a1 += y.y * ea; a2 += y.z * ea; a3 += y.w * ea;
        s0 += y.x; s1 += y.y; s2 += y.z; s3 += y.w;
    }
#pragma unroll
    for (int m = 8; m <= 32; m <<= 1) {
        a0 += __shfl_xor(a0, m, 64); a1 += __shfl_xor(a1, m, 64);
        a2 += __shfl_xor(a2, m, 64); a3 += __shfl_xor(a3, m, 64);
        s0 += __shfl_xor(s0, m, 64); s1 += __shfl_xor(s1, m, 64);
        s2 += __shfl_xor(s2, m, 64); s3 += __shfl_xor(s3, m, 64);
    }
    if (lane < 8) {
        agg8[((size_t)0 * N_NODES + n) * 8 + k] = a0;
        agg8[((size_t)1 * N_NODES + n) * 8 + k] = a1;
        agg8[((size_t)2 * N_NODES + n) * 8 + k] = a2;
        agg8[((size_t)3 * N_NODES + n) * 8 + k] = a3;
    }
    if (lane == 0) {
        sy_arr[(size_t)0 * N_NODES + n] = s0;
        sy_arr[(size_t)1 * N_NODES + n] = s1;
        sy_arr[(size_t)2 * N_NODES + n] = s2;
        sy_arr[(size_t)3 * N_NODES + n] = s3;
    }
}

// ---------------- h0 = x @ node_w + node_b  (f32 + bf16 copies) --------------
__global__ void node_encode_k(const float* __restrict__ x, const float* __restrict__ nw,
                              const float* __restrict__ nb, float* __restrict__ h,
                              unsigned short* __restrict__ h16) {
    int idx = blockIdx.x * 256 + threadIdx.x;
    if (idx >= N_NODES * HID) return;
    int n = idx >> 7, c = idx & 127;
    float acc = nb[c];
#pragma unroll
    for (int k = 0; k < NODE_IN; ++k) acc += x[n * NODE_IN + k] * nw[k * HID + c];
    h[idx] = acc;
    h16[idx] = f2b(acc);
}

// ---------------- gather (bf16 h): gh16[n] = bf16(sum y_l[e]*h16[src[e]]) ----
__global__ __launch_bounds__(256) void gather16_k(
    const int* __restrict__ row_ptr, const int* __restrict__ sorted_src,
    const float* __restrict__ y_l, const unsigned short* __restrict__ h16,
    unsigned int* __restrict__ gh16) {
    int lane = threadIdx.x & 63;
    int gw = (blockIdx.x * 256 + threadIdx.x) >> 6;
    int nw = (gridDim.x * 256) >> 6;
    for (int n = gw; n < N_NODES; n += nw) {
        int ps = row_ptr[n], pe = row_ptr[n + 1];
        float a0 = 0.f, a1 = 0.f;
        int p = ps;
        for (; p + 3 < pe; p += 4) {
            int s0 = sorted_src[p], s1 = sorted_src[p + 1];
            int s2 = sorted_src[p + 2], s3 = sorted_src[p + 3];
            float y0 = y_l[p], y1 = y_l[p + 1], y2 = y_l[p + 2], y3 = y_l[p + 3];
            unsigned int v0 = *(const unsigned int*)(h16 + (size_t)s0 * HID + lane * 2);
            unsigned int v1 = *(const unsigned int*)(h16 + (size_t)s1 * HID + lane * 2);
            unsigned int v2 = *(const unsigned int*)(h16 + (size_t)s2 * HID + lane * 2);
            unsigned int v3 = *(const unsigned int*)(h16 + (size_t)s3 * HID + lane * 2);
            a0 += y0 * b2f((unsigned short)v0); a1 += y0 * b2f((unsigned short)(v0 >> 16));
            a0 += y1 * b2f((unsigned short)v1); a1 += y1 * b2f((unsigned short)(v1 >> 16));
            a0 += y2 * b2f((unsigned short)v2); a1 += y2 * b2f((unsigned short)(v2 >> 16));
            a0 += y3 * b2f((unsigned short)v3); a1 += y3 * b2f((unsigned short)(v3 >> 16));
        }
        for (; p < pe; ++p) {
            float y = y_l[p];
            unsigned int v = *(const unsigned int*)(h16 + (size_t)sorted_src[p] * HID + lane * 2);
            a0 += y * b2f((unsigned short)v);
            a1 += y * b2f((unsigned short)(v >> 16));
        }
        gh16[(size_t)n * 64 + lane] = ((unsigned int)f2b(a1) << 16) | f2b(a0);
    }
}

// ---------------- MFMA GEMM + epilogue (init + LN + relu + residual) ---------
__global__ __launch_bounds__(256) void mfma_ln_k(
    const unsigned short* __restrict__ gh16, const unsigned short* __restrict__ Wt16,
    const float* __restrict__ M_l, const float* __restrict__ cb_l,
    const float* __restrict__ agg8_l, const float* __restrict__ sy_l,
    const float* __restrict__ gm, const float* __restrict__ bt,
    const float* __restrict__ h_in, float* __restrict__ h_out,
    unsigned short* __restrict__ h16_out) {
    const int tid = threadIdx.x;
    const int w = tid >> 6, lane = tid & 63;
    const int g = lane >> 4, c = lane & 15;
    const int nbase = blockIdx.x * 64 + w * 16;

    int arow = nbase + c;
    int arowc = (arow < N_NODES) ? arow : (N_NODES - 1);
    bf16x8 afrag[4];
#pragma unroll
    for (int kc = 0; kc < 4; ++kc)
        afrag[kc] = *(const bf16x8*)(gh16 + (size_t)arowc * HID + kc * 32 + g * 8);

    f32x4 acc[8];
#pragma unroll
    for (int cf = 0; cf < 8; ++cf) acc[cf] = (f32x4){0.f, 0.f, 0.f, 0.f};
#pragma unroll
    for (int cf = 0; cf < 8; ++cf) {
        const unsigned short* wp = Wt16 + (size_t)(cf * 16 + c) * HID + g * 8;
#pragma unroll
        for (int kc = 0; kc < 4; ++kc) {
            bf16x8 bfrag = *(const bf16x8*)(wp + kc * 32);
            acc[cf] = __builtin_amdgcn_mfma_f32_16x16x32_bf16(afrag[kc], bfrag, acc[cf], 0, 0, 0);
        }
    }

    float sy_v[4];
    float a8v[4][8];
#pragma unroll
    for (int r = 0; r < 4; ++r) {
        int node = nbase + 4 * g + r;
        int nc = (node < N_NODES) ? node : (N_NODES - 1);
        sy_v[r] = sy_l[nc];
        float4 t0 = ((const float4*)agg8_l)[(size_t)nc * 2];
        float4 t1 = ((const float4*)agg8_l)[(size_t)nc * 2 + 1];
        a8v[r][0] = t0.x; a8v[r][1] = t0.y; a8v[r][2] = t0.z; a8v[r][3] = t0.w;
        a8v[r][4] = t1.x; a8v[r][5] = t1.y; a8v[r][6] = t1.z; a8v[r][7] = t1.w;
    }
#pragma unroll
    for (int cf = 0; cf < 8; ++cf) {
        int ch = cf * 16 + c;
        float cbv = cb_l[ch];
        float mv[8];
#pragma unroll
        for (int k = 0; k < 8; ++k) mv[k] = M_l[k * HID + ch];
#pragma unroll
        for (int r = 0; r < 4; ++r) {
            float t = sy_v[r] * cbv;
#pragma unroll
            for (int k = 0; k < 8; ++k) t += a8v[r][k] * mv[k];
            acc[cf][r] += t;
        }
    }

    float gav[8], bev[8];
#pragma unroll
    for (int cf = 0; cf < 8; ++cf) {
        gav[cf] = gm[cf * 16 + c];
        bev[cf] = bt[cf * 16 + c];
    }

#pragma unroll
    for (int r = 0; r < 4; ++r) {
        float s = 0.f;
#pragma unroll
        for (int cf = 0; cf < 8; ++cf) s += acc[cf][r];
        s += __shfl_xor(s, 1, 64); s += __shfl_xor(s, 2, 64);
        s += __shfl_xor(s, 4, 64); s += __shfl_xor(s, 8, 64);
        float mean = s * (1.0f / HID);
        float vs = 0.f;
        float d[8];
#pragma unroll
        for (int cf = 0; cf < 8; ++cf) { d[cf] = acc[cf][r] - mean; vs += d[cf] * d[cf]; }
        vs += __shfl_xor(vs, 1, 64); vs += __shfl_xor(vs, 2, 64);
        vs += __shfl_xor(vs, 4, 64); vs += __shfl_xor(vs, 8, 64);
        float rstd = rsqrtf(vs * (1.0f / HID) + LN_EPS);
        int node = nbase + 4 * g + r;
        if (node < N_NODES) {
#pragma unroll
            for (int cf = 0; cf < 8; ++cf) {
                int ch = cf * 16 + c;
                float o = h_in[(size_t)node * HID + ch] +
                          fmaxf(d[cf] * rstd * gav[cf] + bev[cf], 0.f);
                h_out[(size_t)node * HID + ch] = o;
                h16_out[(size_t)node * HID + ch] = f2b(o);
            }
        }
    }
}

extern "C" void kernel_launch(void* const* d_in, const int* in_sizes, int n_in,
                              void* d_out, int out_size, void* d_ws, size_t ws_size,
                              hipStream_t stream) {
    const float* x         = (const float*)d_in[0];
    const void*  ei        = d_in[1];
    const float* edge_attr = (const float*)d_in[2];
    const float* node_w    = (const float*)d_in[3];
    const float* node_b    = (const float*)d_in[4];
    const float* edge_w    = (const float*)d_in[5];
    const float* edge_b    = (const float*)d_in[6];
    const float* lnode_w   = (const float*)d_in[7];
    const float* lnode_b   = (const float*)d_in[8];
    const float* ledge_w   = (const float*)d_in[9];
    const float* ledge_b   = (const float*)d_in[10];
    const float* adm_w     = (const float*)d_in[11];
    const float* adm_b     = (const float*)d_in[12];
    const float* gamma     = (const float*)d_in[13];
    const float* beta      = (const float*)d_in[14];
    float* h = (float*)d_out;

    char* wp = (char*)d_ws;
    auto alloc = [&](size_t bytes) -> void* {
        void* p = (void*)wp;
        wp += (bytes + 255) & ~(size_t)255;
        return p;
    };
    int*            flag       = (int*)alloc(256);
    int*            cursor     = (int*)alloc(sizeof(int) * N_NODES);
    int*            row_ptr    = (int*)alloc(sizeof(int) * (N_NODES + 1));
    int*            partials   = (int*)alloc(sizeof(int) * (SCAN_BLOCKS + 1));
    int*            sorted_src = (int*)alloc(sizeof(int) * N_EDGES);
    int*            sorted_eid = (int*)alloc(sizeof(int) * N_EDGES);
    float4*         y4         = (float4*)alloc(sizeof(float4) * N_EDGES);
    float*          y_sorted   = (float*)alloc(sizeof(float) * NLAYERS * N_EDGES);
    float*          agg8       = (float*)alloc(sizeof(float) * NLAYERS * N_NODES * 8);
    float*          sy_arr     = (float*)alloc(sizeof(float) * NLAYERS * N_NODES);
    float*          Mw         = (float*)alloc(sizeof(float) * NLAYERS * 8 * HID);
    float*          cbw        = (float*)alloc(sizeof(float) * NLAYERS * HID);
    float*          vw         = (float*)alloc(sizeof(float) * NLAYERS * 8);
    float*          cgate      = (float*)alloc(sizeof(float) * NLAYERS);
    float*          hbuf       = (float*)alloc(sizeof(float) * (size_t)N_NODES * HID);
    unsigned short* h16        = (unsigned short*)alloc(sizeof(short) * (size_t)N_NODES * HID);
    unsigned short* gh16       = (unsigned short*)alloc(sizeof(short) * (size_t)N_NODES * HID);
    unsigned short* Wt16       = (unsigned short*)alloc(sizeof(short) * NLAYERS * HID * HID);
    (void)ws_size; (void)in_sizes; (void)n_in; (void)out_size;

    hipMemsetAsync(cursor, 0, sizeof(int) * N_NODES, stream);
    detect_i64<<<1, 256, 0, stream>>>((const int*)ei, flag);
    hist_k<<<(N_EDGES + 255) / 256, 256, 0, stream>>>(ei, flag, cursor);
    scan1_k<<<SCAN_BLOCKS, 256, 0, stream>>>(cursor, row_ptr, partials);
    scan2_k<<<1, 256, 0, stream>>>(partials);
    scan3_k<<<SCAN_BLOCKS, 256, 0, stream>>>(row_ptr, cursor, partials);
    place_k<<<(N_EDGES + 255) / 256, 256, 0, stream>>>(ei, flag, cursor, sorted_src, sorted_eid);
    precompute_k<<<19, 256, 0, stream>>>(edge_w, edge_b, ledge_w, ledge_b, lnode_b,
                                         adm_w, adm_b, Mw, cbw, vw, cgate);
    convertw_k<<<(NLAYERS * HID * HID + 255) / 256, 256, 0, stream>>>(lnode_w, Wt16);
    yorig_k<<<(N_EDGES + 255) / 256, 256, 0, stream>>>(edge_attr, vw, cgate, y4);
    node_stats_k<<<(N_NODES + 3) / 4, 256, 0, stream>>>(row_ptr, sorted_eid, edge_attr, y4,
                                                        agg8, sy_arr, y_sorted);
    node_encode_k<<<(N_NODES * HID + 255) / 256, 256, 0, stream>>>(x, node_w, node_b, h, h16);

    float* hin = h;
    float* hout = hbuf;
    for (int l = 0; l < NLAYERS; ++l) {
        gather16_k<<<2048, 256, 0, stream>>>(
            row_ptr, sorted_src, y_sorted + (size_t)l * N_EDGES, h16, (unsigned int*)gh16);
        mfma_ln_k<<<(N_NODES + 63) / 64, 256, 0, stream>>>(
            gh16, Wt16 + (size_t)l * HID * HID,
            Mw + (size_t)l * 8 * HID, cbw + (size_t)l * HID,
            agg8 + (size_t)l * N_NODES * 8, sy_arr + (size_t)l * N_NODES,
            gamma + (size_t)l * HID, beta + (size_t)l * HID,
            hin, hout, h16);
        float* t = hin; hin = hout; hout = t;
    }
    // NLAYERS even -> final f32 result lands in d_out
}

// Round 6
// 410.267 us; speedup vs baseline: 3.2532x; 1.0273x over previous
//
#include <hip/hip_runtime.h>
#include <math.h>

#define N_NODES 50000
#define N_EDGES 600000
#define HID 128
#define NLAYERS 4
#define NODE_IN 16
#define EDGE_IN 8
#define LN_EPS 1e-5f
#define SCAN_BLOCKS ((N_NODES + 255) / 256)

typedef short bf16x8 __attribute__((ext_vector_type(8)));
typedef float f32x4 __attribute__((ext_vector_type(4)));

__device__ __forceinline__ float b2f(unsigned short u) {
    union { unsigned int i; float f; } v; v.i = ((unsigned int)u) << 16; return v.f;
}
__device__ __forceinline__ unsigned short f2b(float x) {
    union { float f; unsigned int i; } v; v.f = x;
    unsigned int b = v.i + 0x7FFFu + ((v.i >> 16) & 1u);
    return (unsigned short)(b >> 16);
}

// ---------------- edge_index dtype detection (int32 vs int64) ----------------
__global__ void detect_i64(const int* ei, int* flag) {
    __shared__ int nz;
    if (threadIdx.x == 0) nz = 0;
    __syncthreads();
    int acc = 0;
    for (int i = threadIdx.x; i < 1024; i += blockDim.x)
        if (ei[2 * i + 1] != 0) acc = 1;
    if (acc) atomicOr(&nz, 1);
    __syncthreads();
    if (threadIdx.x == 0) *flag = (nz == 0) ? 1 : 0;
}

__device__ __forceinline__ int edge_src(const void* ei, int f, int e) {
    if (f) return (int)((const long long*)ei)[e];
    return ((const int*)ei)[e];
}
__device__ __forceinline__ int edge_dst(const void* ei, int f, int e) {
    if (f) return (int)((const long long*)ei)[N_EDGES + e];
    return ((const int*)ei)[N_EDGES + e];
}

// ---------------- CSR build ----------------
__global__ void hist_k(const void* ei, const int* flag, int* cursor) {
    int e = blockIdx.x * blockDim.x + threadIdx.x;
    if (e >= N_EDGES) return;
    int f = *flag;
    atomicAdd(&cursor[edge_dst(ei, f, e)], 1);
}

__global__ void scan1_k(const int* __restrict__ cursor, int* __restrict__ locex,
                        int* __restrict__ partials) {
    __shared__ int sd[256];
    int t = threadIdx.x, i = blockIdx.x * 256 + t;
    int v = (i < N_NODES) ? cursor[i] : 0;
    sd[t] = v;
    __syncthreads();
    for (int off = 1; off < 256; off <<= 1) {
        int x = (t >= off) ? sd[t - off] : 0;
        __syncthreads();
        sd[t] += x;
        __syncthreads();
    }
    if (i < N_NODES) locex[i] = sd[t] - v;
    if (t == 255) partials[blockIdx.x] = sd[255];
}

__global__ void scan2_k(int* partials) {
    __shared__ int sd[256];
    int t = threadIdx.x;
    int v = (t < SCAN_BLOCKS) ? partials[t] : 0;
    sd[t] = v;
    __syncthreads();
    for (int off = 1; off < 256; off <<= 1) {
        int x = (t >= off) ? sd[t - off] : 0;
        __syncthreads();
        sd[t] += x;
        __syncthreads();
    }
    if (t < SCAN_BLOCKS) partials[t] = sd[t] - v;
    if (t == 255) partials[SCAN_BLOCKS] = sd[255];
}

__global__ void scan3_k(int* __restrict__ row_ptr, int* __restrict__ cursor,
                        const int* __restrict__ partials) {
    int i = blockIdx.x * 256 + threadIdx.x;
    if (i < N_NODES) {
        int r = row_ptr[i] + partials[blockIdx.x];
        row_ptr[i] = r;
        cursor[i] = r;
    }
    if (i == N_NODES) row_ptr[N_NODES] = partials[SCAN_BLOCKS];
}

// place + direct scatter of per-layer gates into sorted order
__global__ void place_k(const void* ei, const int* flag, int* cursor,
                        const float4* __restrict__ y4,
                        int* sorted_src, int* sorted_eid,
                        float* __restrict__ y_sorted) {
    int e = blockIdx.x * blockDim.x + threadIdx.x;
    if (e >= N_EDGES) return;
    int f = *flag;
    int s = edge_src(ei, f, e);
    int d = edge_dst(ei, f, e);
    int pos = atomicAdd(&cursor[d], 1);
    sorted_src[pos] = s;
    sorted_eid[pos] = e;
    float4 y = y4[e];
    y_sorted[(size_t)0 * N_EDGES + pos] = y.x;
    y_sorted[(size_t)1 * N_EDGES + pos] = y.y;
    y_sorted[(size_t)2 * N_EDGES + pos] = y.z;
    y_sorted[(size_t)3 * N_EDGES + pos] = y.w;
}

// ---------------- weight precompute (f32 epilogue constants) ----------------
__global__ void precompute_k(const float* __restrict__ edge_w, const float* __restrict__ edge_b,
                             const float* __restrict__ ledge_w, const float* __restrict__ ledge_b,
                             const float* __restrict__ lnode_b,
                             const float* __restrict__ adm_w, const float* __restrict__ adm_b,
                             float* __restrict__ M, float* __restrict__ cb,
                             float* __restrict__ v, float* __restrict__ cgate) {
    int t = blockIdx.x * 256 + threadIdx.x;
    if (t < 4096) {
        int l = t >> 10, k = (t >> 7) & 7, ch = t & 127;
        const float* lw = ledge_w + (size_t)l * HID * HID;
        float a = 0.f;
        for (int j = 0; j < HID; ++j) a += edge_w[k * HID + j] * lw[j * HID + ch];
        M[t] = a;
    } else if (t < 4608) {
        int u = t - 4096;
        int l = u >> 7, ch = u & 127;
        const float* lw = ledge_w + (size_t)l * HID * HID;
        float a = ledge_b[l * HID + ch] + lnode_b[l * HID + ch];
        for (int j = 0; j < HID; ++j) a += edge_b[j] * lw[j * HID + ch];
        cb[u] = a;
    } else if (t < 4640) {
        int u = t - 4608;
        int l = u >> 3, k = u & 7;
        float a = 0.f;
        for (int j = 0; j < HID; ++j) a += edge_w[k * HID + j] * adm_w[l * HID + j];
        v[u] = a;
    } else if (t < 4644) {
        int l = t - 4640;
        float a = adm_b[l];
        for (int j = 0; j < HID; ++j) a += edge_b[j] * adm_w[l * HID + j];
        cgate[l] = a;
    }
}

// ---- W^T bf16: Wt16[l][n][k] = bf16(lnode_w[l][k][n]) (B-operand, k-contig) --
__global__ void convertw_k(const float* __restrict__ lnode_w, unsigned short* __restrict__ Wt16) {
    int idx = blockIdx.x * 256 + threadIdx.x;
    if (idx >= NLAYERS * HID * HID) return;
    int l = idx >> 14, r = idx & 16383, n = r >> 7, k = r & 127;
    Wt16[idx] = f2b(lnode_w[(size_t)l * HID * HID + k * HID + n]);
}

// ---------------- per-edge gates (original edge order) ----------------
__global__ __launch_bounds__(256) void yorig_k(const float* __restrict__ edge_attr,
                                               const float* __restrict__ v,
                                               const float* __restrict__ cgate,
                                               float4* __restrict__ y4) {
    __shared__ float sv[36];
    if (threadIdx.x < 32) sv[threadIdx.x] = v[threadIdx.x];
    else if (threadIdx.x < 36) sv[threadIdx.x] = cgate[threadIdx.x - 32];
    __syncthreads();
    int e = blockIdx.x * 256 + threadIdx.x;
    if (e >= N_EDGES) return;
    float4 a0 = ((const float4*)edge_attr)[(size_t)e * 2];
    float4 a1 = ((const float4*)edge_attr)[(size_t)e * 2 + 1];
    float pr[NLAYERS];
#pragma unroll
    for (int l = 0; l < NLAYERS; ++l) {
        const float* vl = &sv[l * 8];
        float p = sv[32 + l];
        p += a0.x * vl[0] + a0.y * vl[1] + a0.z * vl[2] + a0.w * vl[3];
        p += a1.x * vl[4] + a1.y * vl[5] + a1.z * vl[6] + a1.w * vl[7];
        pr[l] = 1.0f / (1.0f + expf(-p));
    }
    y4[e] = make_float4(pr[0], pr[1], pr[2], pr[3]);
}

// ---------------- per-node edge stats: one wave per node (exact grid) -------
__global__ __launch_bounds__(256) void node_stats_k(
    const int* __restrict__ row_ptr, const int* __restrict__ sorted_eid,
    const float* __restrict__ edge_attr, const float* __restrict__ y_sorted,
    float* __restrict__ agg8, float* __restrict__ sy_arr) {
    int lane = threadIdx.x & 63;
    int n = (blockIdx.x * 256 + threadIdx.x) >> 6;
    int es = lane >> 3, k = lane & 7;
    int ps = row_ptr[n], pe = row_ptr[n + 1];
    float a0 = 0.f, a1 = 0.f, a2 = 0.f, a3 = 0.f;
    float s0 = 0.f, s1 = 0.f, s2 = 0.f, s3 = 0.f;
    for (int p = ps + es; p < pe; p += 8) {
        int eid = sorted_eid[p];
        float ea = edge_attr[(size_t)eid * EDGE_IN + k];
        float y0 = y_sorted[(size_t)0 * N_EDGES + p];
        float y1 = y_sorted[(size_t)1 * N_EDGES + p];
        float y2 = y_sorted[(size_t)2 * N_EDGES + p];
        float y3 = y_sorted[(size_t)3 * N_EDGES + p];
        a0 += y0 * ea; a1 += y1 * ea; a2 += y2 * ea; a3 += y3 * ea;
        s0 += y0; s1 += y1; s2 += y2; s3 += y3;
    }
#pragma unroll
    for (int m = 8; m <= 32; m <<= 1) {
        a0 += __shfl_xor(a0, m, 64); a1 += __shfl_xor(a1, m, 64);
        a2 += __shfl_xor(a2, m, 64); a3 += __shfl_xor(a3, m, 64);
        s0 += __shfl_xor(s0, m, 64); s1 += __shfl_xor(s1, m, 64);
        s2 += __shfl_xor(s2, m, 64); s3 += __shfl_xor(s3, m, 64);
    }
    if (lane < 8) {
        agg8[((size_t)0 * N_NODES + n) * 8 + k] = a0;
        agg8[((size_t)1 * N_NODES + n) * 8 + k] = a1;
        agg8[((size_t)2 * N_NODES + n) * 8 + k] = a2;
        agg8[((size_t)3 * N_NODES + n) * 8 + k] = a3;
    }
    if (lane == 0) {
        sy_arr[(size_t)0 * N_NODES + n] = s0;
        sy_arr[(size_t)1 * N_NODES + n] = s1;
        sy_arr[(size_t)2 * N_NODES + n] = s2;
        sy_arr[(size_t)3 * N_NODES + n] = s3;
    }
}

// ---------------- h0 = x @ node_w + node_b  (f32 + bf16 copies) --------------
__global__ void node_encode_k(const float* __restrict__ x, const float* __restrict__ nw,
                              const float* __restrict__ nb, float* __restrict__ h,
                              unsigned short* __restrict__ h16) {
    int idx = blockIdx.x * 256 + threadIdx.x;
    if (idx >= N_NODES * HID) return;
    int n = idx >> 7, c = idx & 127;
    float acc = nb[c];
#pragma unroll
    for (int k = 0; k < NODE_IN; ++k) acc += x[n * NODE_IN + k] * nw[k * HID + c];
    h[idx] = acc;
    h16[idx] = f2b(acc);
}

// ---------------- gather (bf16 h): wave per node, exact grid -----------------
__global__ __launch_bounds__(256) void gather16_k(
    const int* __restrict__ row_ptr, const int* __restrict__ sorted_src,
    const float* __restrict__ y_l, const unsigned short* __restrict__ h16,
    unsigned int* __restrict__ gh16) {
    int lane = threadIdx.x & 63;
    int n = (blockIdx.x * 256 + threadIdx.x) >> 6;
    int ps = row_ptr[n], pe = row_ptr[n + 1];
    float a0 = 0.f, a1 = 0.f;
    int p = ps;
    for (; p + 3 < pe; p += 4) {
        int s0 = sorted_src[p], s1 = sorted_src[p + 1];
        int s2 = sorted_src[p + 2], s3 = sorted_src[p + 3];
        float y0 = y_l[p], y1 = y_l[p + 1], y2 = y_l[p + 2], y3 = y_l[p + 3];
        unsigned int v0 = *(const unsigned int*)(h16 + (size_t)s0 * HID + lane * 2);
        unsigned int v1 = *(const unsigned int*)(h16 + (size_t)s1 * HID + lane * 2);
        unsigned int v2 = *(const unsigned int*)(h16 + (size_t)s2 * HID + lane * 2);
        unsigned int v3 = *(const unsigned int*)(h16 + (size_t)s3 * HID + lane * 2);
        a0 += y0 * b2f((unsigned short)v0); a1 += y0 * b2f((unsigned short)(v0 >> 16));
        a0 += y1 * b2f((unsigned short)v1); a1 += y1 * b2f((unsigned short)(v1 >> 16));
        a0 += y2 * b2f((unsigned short)v2); a1 += y2 * b2f((unsigned short)(v2 >> 16));
        a0 += y3 * b2f((unsigned short)v3); a1 += y3 * b2f((unsigned short)(v3 >> 16));
    }
    for (; p < pe; ++p) {
        float y = y_l[p];
        unsigned int v = *(const unsigned int*)(h16 + (size_t)sorted_src[p] * HID + lane * 2);
        a0 += y * b2f((unsigned short)v);
        a1 += y * b2f((unsigned short)(v >> 16));
    }
    gh16[(size_t)n * 64 + lane] = ((unsigned int)f2b(a1) << 16) | f2b(a0);
}

// ---------------- MFMA GEMM + epilogue: 16 nodes/block, wave = 32 channels ---
// Wave w owns column tiles cf = {2w, 2w+1}. LN is cross-wave via 512B LDS
// (sum x, sum x^2). Grid = 3125 blocks exactly (no bounds checks).
__global__ __launch_bounds__(256) void mfma_ln_k(
    const unsigned short* __restrict__ gh16, const unsigned short* __restrict__ Wt16,
    const float* __restrict__ M_l, const float* __restrict__ cb_l,
    const float* __restrict__ agg8_l, const float* __restrict__ sy_l,
    const float* __restrict__ gm, const float* __restrict__ bt,
    const float* __restrict__ h_in, float* __restrict__ h_out,
    unsigned short* __restrict__ h16_out) {
    __shared__ float red[4][16][2];
    const int tid = threadIdx.x;
    const int w = tid >> 6, lane = tid & 63;
    const int g = lane >> 4, c = lane & 15;
    const int nbase = blockIdx.x * 16;
    const int cf0 = w * 2;

    // A fragments: 16 rows (nbase..nbase+15), k = kc*32 + g*8 + j
    bf16x8 afrag[4];
#pragma unroll
    for (int kc = 0; kc < 4; ++kc)
        afrag[kc] = *(const bf16x8*)(gh16 + (size_t)(nbase + c) * HID + kc * 32 + g * 8);

    // 8 MFMAs: 2 column tiles x 4 k-chunks
    f32x4 acc[2];
#pragma unroll
    for (int t = 0; t < 2; ++t) {
        acc[t] = (f32x4){0.f, 0.f, 0.f, 0.f};
        const unsigned short* wp = Wt16 + (size_t)((cf0 + t) * 16 + c) * HID + g * 8;
#pragma unroll
        for (int kc = 0; kc < 4; ++kc) {
            bf16x8 bfrag = *(const bf16x8*)(wp + kc * 32);
            acc[t] = __builtin_amdgcn_mfma_f32_16x16x32_bf16(afrag[kc], bfrag, acc[t], 0, 0, 0);
        }
    }

    // epilogue constants for this wave's 2 channels-of-16
    float cbv[2], gav[2], bev[2], mv[2][8];
#pragma unroll
    for (int t = 0; t < 2; ++t) {
        int ch = (cf0 + t) * 16 + c;
        cbv[t] = cb_l[ch]; gav[t] = gm[ch]; bev[t] = bt[ch];
#pragma unroll
        for (int k = 0; k < 8; ++k) mv[t][k] = M_l[k * HID + ch];
    }
    // init: acc += sy*cb + agg8 @ M (rows 4g+r)
#pragma unroll
    for (int r = 0; r < 4; ++r) {
        int node = nbase + 4 * g + r;
        float sy = sy_l[node];
        float4 t0 = ((const float4*)agg8_l)[(size_t)node * 2];
        float4 t1 = ((const float4*)agg8_l)[(size_t)node * 2 + 1];
        float a8[8] = {t0.x, t0.y, t0.z, t0.w, t1.x, t1.y, t1.z, t1.w};
#pragma unroll
        for (int t = 0; t < 2; ++t) {
            float v = sy * cbv[t];
#pragma unroll
            for (int k = 0; k < 8; ++k) v += a8[k] * mv[t][k];
            acc[t][r] += v;
        }
    }

    // LN partials: per-row sum x, sum x^2 over this wave's 32 channels
    float sx[4], sq[4];
#pragma unroll
    for (int r = 0; r < 4; ++r) {
        sx[r] = acc[0][r] + acc[1][r];
        sq[r] = acc[0][r] * acc[0][r] + acc[1][r] * acc[1][r];
    }
#pragma unroll
    for (int m = 1; m <= 8; m <<= 1) {
#pragma unroll
        for (int r = 0; r < 4; ++r) {
            sx[r] += __shfl_xor(sx[r], m, 64);
            sq[r] += __shfl_xor(sq[r], m, 64);
        }
    }
    if (c == 0) {
#pragma unroll
        for (int r = 0; r < 4; ++r) {
            red[w][4 * g + r][0] = sx[r];
            red[w][4 * g + r][1] = sq[r];
        }
    }
    __syncthreads();

#pragma unroll
    for (int r = 0; r < 4; ++r) {
        int row = 4 * g + r;
        float SX = red[0][row][0] + red[1][row][0] + red[2][row][0] + red[3][row][0];
        float SQ = red[0][row][1] + red[1][row][1] + red[2][row][1] + red[3][row][1];
        float mean = SX * (1.0f / HID);
        float var = SQ * (1.0f / HID) - mean * mean;
        float rstd = rsqrtf(var + LN_EPS);
        int node = nbase + row;
#pragma unroll
        for (int t = 0; t < 2; ++t) {
            int ch = (cf0 + t) * 16 + c;
            float d = acc[t][r] - mean;
            float o = h_in[(size_t)node * HID + ch] +
                      fmaxf(d * rstd * gav[t] + bev[t], 0.f);
            h_out[(size_t)node * HID + ch] = o;
            h16_out[(size_t)node * HID + ch] = f2b(o);
        }
    }
}

extern "C" void kernel_launch(void* const* d_in, const int* in_sizes, int n_in,
                              void* d_out, int out_size, void* d_ws, size_t ws_size,
                              hipStream_t stream) {
    const float* x         = (const float*)d_in[0];
    const void*  ei        = d_in[1];
    const float* edge_attr = (const float*)d_in[2];
    const float* node_w    = (const float*)d_in[3];
    const float* node_b    = (const float*)d_in[4];
    const float* edge_w    = (const float*)d_in[5];
    const float* edge_b    = (const float*)d_in[6];
    const float* lnode_w   = (const float*)d_in[7];
    const float* lnode_b   = (const float*)d_in[8];
    const float* ledge_w   = (const float*)d_in[9];
    const float* ledge_b   = (const float*)d_in[10];
    const float* adm_w     = (const float*)d_in[11];
    const float* adm_b     = (const float*)d_in[12];
    const float* gamma     = (const float*)d_in[13];
    const float* beta      = (const float*)d_in[14];
    float* h = (float*)d_out;

    char* wp = (char*)d_ws;
    auto alloc = [&](size_t bytes) -> void* {
        void* p = (void*)wp;
        wp += (bytes + 255) & ~(size_t)255;
        return p;
    };
    int*            flag       = (int*)alloc(256);
    int*            cursor     = (int*)alloc(sizeof(int) * N_NODES);
    int*            row_ptr    = (int*)alloc(sizeof(int) * (N_NODES + 1));
    int*            partials   = (int*)alloc(sizeof(int) * (SCAN_BLOCKS + 1));
    int*            sorted_src = (int*)alloc(sizeof(int) * N_EDGES);
    int*            sorted_eid = (int*)alloc(sizeof(int) * N_EDGES);
    float4*         y4         = (float4*)alloc(sizeof(float4) * N_EDGES);
    float*          y_sorted   = (float*)alloc(sizeof(float) * NLAYERS * N_EDGES);
    float*          agg8       = (float*)alloc(sizeof(float) * NLAYERS * N_NODES * 8);
    float*          sy_arr     = (float*)alloc(sizeof(float) * NLAYERS * N_NODES);
    float*          Mw         = (float*)alloc(sizeof(float) * NLAYERS * 8 * HID);
    float*          cbw        = (float*)alloc(sizeof(float) * NLAYERS * HID);
    float*          vw         = (float*)alloc(sizeof(float) * NLAYERS * 8);
    float*          cgate      = (float*)alloc(sizeof(float) * NLAYERS);
    float*          hbuf       = (float*)alloc(sizeof(float) * (size_t)N_NODES * HID);
    unsigned short* h16        = (unsigned short*)alloc(sizeof(short) * (size_t)N_NODES * HID);
    unsigned short* gh16       = (unsigned short*)alloc(sizeof(short) * (size_t)N_NODES * HID);
    unsigned short* Wt16       = (unsigned short*)alloc(sizeof(short) * NLAYERS * HID * HID);
    (void)ws_size; (void)in_sizes; (void)n_in; (void)out_size;

    hipMemsetAsync(cursor, 0, sizeof(int) * N_NODES, stream);
    detect_i64<<<1, 256, 0, stream>>>((const int*)ei, flag);
    hist_k<<<(N_EDGES + 255) / 256, 256, 0, stream>>>(ei, flag, cursor);
    scan1_k<<<SCAN_BLOCKS, 256, 0, stream>>>(cursor, row_ptr, partials);
    scan2_k<<<1, 256, 0, stream>>>(partials);
    scan3_k<<<SCAN_BLOCKS, 256, 0, stream>>>(row_ptr, cursor, partials);
    precompute_k<<<19, 256, 0, stream>>>(edge_w, edge_b, ledge_w, ledge_b, lnode_b,
                                         adm_w, adm_b, Mw, cbw, vw, cgate);
    convertw_k<<<(NLAYERS * HID * HID + 255) / 256, 256, 0, stream>>>(lnode_w, Wt16);
    yorig_k<<<(N_EDGES + 255) / 256, 256, 0, stream>>>(edge_attr, vw, cgate, y4);
    place_k<<<(N_EDGES + 255) / 256, 256, 0, stream>>>(ei, flag, cursor, y4,
                                                       sorted_src, sorted_eid, y_sorted);
    node_stats_k<<<N_NODES / 4, 256, 0, stream>>>(row_ptr, sorted_eid, edge_attr,
                                                  y_sorted, agg8, sy_arr);
    node_encode_k<<<(N_NODES * HID + 255) / 256, 256, 0, stream>>>(x, node_w, node_b, h, h16);

    float* hin = h;
    float* hout = hbuf;
    for (int l = 0; l < NLAYERS; ++l) {
        gather16_k<<<N_NODES / 4, 256, 0, stream>>>(
            row_ptr, sorted_src, y_sorted + (size_t)l * N_EDGES, h16, (unsigned int*)gh16);
        mfma_ln_k<<<N_NODES / 16, 256, 0, stream>>>(
            gh16, Wt16 + (size_t)l * HID * HID,
            Mw + (size_t)l * 8 * HID, cbw + (size_t)l * HID,
            agg8 + (size_t)l * N_NODES * 8, sy_arr + (size_t)l * N_NODES,
            gamma + (size_t)l * HID, beta + (size_t)l * HID,
            hin, hout, h16);
        float* t = hin; hin = hout; hout = t;
    }
    // NLAYERS even -> final f32 result lands in d_out
}

// Round 7
// 390.785 us; speedup vs baseline: 3.4153x; 1.0499x over previous
//
#include <hip/hip_runtime.h>
#include <math.h>

#define N_NODES 50000
#define N_EDGES 600000
#define HID 128
#define NLAYERS 4
#define NODE_IN 16
#define EDGE_IN 8
#define LN_EPS 1e-5f
#define SCAN_BLOCKS ((N_NODES + 255) / 256)

typedef short bf16x8 __attribute__((ext_vector_type(8)));
typedef float f32x4 __attribute__((ext_vector_type(4)));

__device__ __forceinline__ float b2f(unsigned short u) {
    union { unsigned int i; float f; } v; v.i = ((unsigned int)u) << 16; return v.f;
}
__device__ __forceinline__ unsigned short f2b(float x) {
    union { float f; unsigned int i; } v; v.f = x;
    unsigned int b = v.i + 0x7FFFu + ((v.i >> 16) & 1u);
    return (unsigned short)(b >> 16);
}

// ---------------- edge_index dtype detection (int32 vs int64) ----------------
__global__ void detect_i64(const int* ei, int* flag) {
    __shared__ int nz;
    if (threadIdx.x == 0) nz = 0;
    __syncthreads();
    int acc = 0;
    for (int i = threadIdx.x; i < 1024; i += blockDim.x)
        if (ei[2 * i + 1] != 0) acc = 1;
    if (acc) atomicOr(&nz, 1);
    __syncthreads();
    if (threadIdx.x == 0) *flag = (nz == 0) ? 1 : 0;
}

__device__ __forceinline__ int edge_src(const void* ei, int f, int e) {
    if (f) return (int)((const long long*)ei)[e];
    return ((const int*)ei)[e];
}
__device__ __forceinline__ int edge_dst(const void* ei, int f, int e) {
    if (f) return (int)((const long long*)ei)[N_EDGES + e];
    return ((const int*)ei)[N_EDGES + e];
}

// ---------------- CSR build ----------------
__global__ void hist_k(const void* ei, const int* flag, int* cursor) {
    int e = blockIdx.x * blockDim.x + threadIdx.x;
    if (e >= N_EDGES) return;
    int f = *flag;
    atomicAdd(&cursor[edge_dst(ei, f, e)], 1);
}

__global__ void scan1_k(const int* __restrict__ cursor, int* __restrict__ locex,
                        int* __restrict__ partials) {
    __shared__ int sd[256];
    int t = threadIdx.x, i = blockIdx.x * 256 + t;
    int v = (i < N_NODES) ? cursor[i] : 0;
    sd[t] = v;
    __syncthreads();
    for (int off = 1; off < 256; off <<= 1) {
        int x = (t >= off) ? sd[t - off] : 0;
        __syncthreads();
        sd[t] += x;
        __syncthreads();
    }
    if (i < N_NODES) locex[i] = sd[t] - v;
    if (t == 255) partials[blockIdx.x] = sd[255];
}

__global__ void scan2_k(int* partials) {
    __shared__ int sd[256];
    int t = threadIdx.x;
    int v = (t < SCAN_BLOCKS) ? partials[t] : 0;
    sd[t] = v;
    __syncthreads();
    for (int off = 1; off < 256; off <<= 1) {
        int x = (t >= off) ? sd[t - off] : 0;
        __syncthreads();
        sd[t] += x;
        __syncthreads();
    }
    if (t < SCAN_BLOCKS) partials[t] = sd[t] - v;
    if (t == 255) partials[SCAN_BLOCKS] = sd[255];
}

__global__ void scan3_k(int* __restrict__ row_ptr, int* __restrict__ cursor,
                        const int* __restrict__ partials) {
    int i = blockIdx.x * 256 + threadIdx.x;
    if (i < N_NODES) {
        int r = row_ptr[i] + partials[blockIdx.x];
        row_ptr[i] = r;
        cursor[i] = r;
    }
    if (i == N_NODES) row_ptr[N_NODES] = partials[SCAN_BLOCKS];
}

__global__ void place_k(const void* ei, const int* flag, int* cursor,
                        int* sorted_src, int* sorted_eid) {
    int e = blockIdx.x * blockDim.x + threadIdx.x;
    if (e >= N_EDGES) return;
    int f = *flag;
    int s = edge_src(ei, f, e);
    int d = edge_dst(ei, f, e);
    int pos = atomicAdd(&cursor[d], 1);
    sorted_src[pos] = s;
    sorted_eid[pos] = e;
}

// ---------------- weight precompute (f32 epilogue constants) ----------------
__global__ void precompute_k(const float* __restrict__ edge_w, const float* __restrict__ edge_b,
                             const float* __restrict__ ledge_w, const float* __restrict__ ledge_b,
                             const float* __restrict__ lnode_b,
                             const float* __restrict__ adm_w, const float* __restrict__ adm_b,
                             float* __restrict__ M, float* __restrict__ cb,
                             float* __restrict__ v, float* __restrict__ cgate) {
    int t = blockIdx.x * 256 + threadIdx.x;
    if (t < 4096) {
        int l = t >> 10, k = (t >> 7) & 7, ch = t & 127;
        const float* lw = ledge_w + (size_t)l * HID * HID;
        float a = 0.f;
        for (int j = 0; j < HID; ++j) a += edge_w[k * HID + j] * lw[j * HID + ch];
        M[t] = a;
    } else if (t < 4608) {
        int u = t - 4096;
        int l = u >> 7, ch = u & 127;
        const float* lw = ledge_w + (size_t)l * HID * HID;
        float a = ledge_b[l * HID + ch] + lnode_b[l * HID + ch];
        for (int j = 0; j < HID; ++j) a += edge_b[j] * lw[j * HID + ch];
        cb[u] = a;
    } else if (t < 4640) {
        int u = t - 4608;
        int l = u >> 3, k = u & 7;
        float a = 0.f;
        for (int j = 0; j < HID; ++j) a += edge_w[k * HID + j] * adm_w[l * HID + j];
        v[u] = a;
    } else if (t < 4644) {
        int l = t - 4640;
        float a = adm_b[l];
        for (int j = 0; j < HID; ++j) a += edge_b[j] * adm_w[l * HID + j];
        cgate[l] = a;
    }
}

// ---- W^T bf16: Wt16[l][n][k] = bf16(lnode_w[l][k][n]) (B-operand, k-contig) --
__global__ void convertw_k(const float* __restrict__ lnode_w, unsigned short* __restrict__ Wt16) {
    int idx = blockIdx.x * 256 + threadIdx.x;
    if (idx >= NLAYERS * HID * HID) return;
    int l = idx >> 14, r = idx & 16383, n = r >> 7, k = r & 127;
    Wt16[idx] = f2b(lnode_w[(size_t)l * HID * HID + k * HID + n]);
}

// ---------------- per-node edge stats + fused gates: one wave per node -------
// lane = 8*es + k. Gate dot over k via shfl_xor(1,2,4); y_l written in CSR
// order; agg8/sy reduced over es via shfl_xor(8,16,32).
__global__ __launch_bounds__(256) void node_stats_k(
    const int* __restrict__ row_ptr, const int* __restrict__ sorted_eid,
    const float* __restrict__ edge_attr, const float* __restrict__ vw,
    const float* __restrict__ cgate,
    float* __restrict__ agg8, float* __restrict__ sy_arr,
    float* __restrict__ y_sorted) {
    int lane = threadIdx.x & 63;
    int n = (blockIdx.x * 256 + threadIdx.x) >> 6;
    int es = lane >> 3, k = lane & 7;
    float v0 = vw[0 * 8 + k], v1 = vw[1 * 8 + k], v2 = vw[2 * 8 + k], v3 = vw[3 * 8 + k];
    float c0 = cgate[0], c1 = cgate[1], c2 = cgate[2], c3 = cgate[3];
    int ps = row_ptr[n], pe = row_ptr[n + 1];
    float a0 = 0.f, a1 = 0.f, a2 = 0.f, a3 = 0.f;
    float s0 = 0.f, s1 = 0.f, s2 = 0.f, s3 = 0.f;
    for (int p = ps + es; p < pe; p += 8) {
        int eid = sorted_eid[p];
        float ea = edge_attr[(size_t)eid * EDGE_IN + k];
        float t0 = ea * v0, t1 = ea * v1, t2 = ea * v2, t3 = ea * v3;
#pragma unroll
        for (int m = 1; m <= 4; m <<= 1) {
            t0 += __shfl_xor(t0, m, 64); t1 += __shfl_xor(t1, m, 64);
            t2 += __shfl_xor(t2, m, 64); t3 += __shfl_xor(t3, m, 64);
        }
        float y0 = 1.0f / (1.0f + expf(-(t0 + c0)));
        float y1 = 1.0f / (1.0f + expf(-(t1 + c1)));
        float y2 = 1.0f / (1.0f + expf(-(t2 + c2)));
        float y3 = 1.0f / (1.0f + expf(-(t3 + c3)));
        if (k < 4) {
            float yk = (k == 0) ? y0 : (k == 1) ? y1 : (k == 2) ? y2 : y3;
            y_sorted[(size_t)k * N_EDGES + p] = yk;
        }
        a0 += y0 * ea; a1 += y1 * ea; a2 += y2 * ea; a3 += y3 * ea;
        s0 += y0; s1 += y1; s2 += y2; s3 += y3;
    }
#pragma unroll
    for (int m = 8; m <= 32; m <<= 1) {
        a0 += __shfl_xor(a0, m, 64); a1 += __shfl_xor(a1, m, 64);
        a2 += __shfl_xor(a2, m, 64); a3 += __shfl_xor(a3, m, 64);
        s0 += __shfl_xor(s0, m, 64); s1 += __shfl_xor(s1, m, 64);
        s2 += __shfl_xor(s2, m, 64); s3 += __shfl_xor(s3, m, 64);
    }
    if (lane < 8) {
        agg8[((size_t)0 * N_NODES + n) * 8 + k] = a0;
        agg8[((size_t)1 * N_NODES + n) * 8 + k] = a1;
        agg8[((size_t)2 * N_NODES + n) * 8 + k] = a2;
        agg8[((size_t)3 * N_NODES + n) * 8 + k] = a3;
    }
    if (lane == 0) {
        sy_arr[(size_t)0 * N_NODES + n] = s0;
        sy_arr[(size_t)1 * N_NODES + n] = s1;
        sy_arr[(size_t)2 * N_NODES + n] = s2;
        sy_arr[(size_t)3 * N_NODES + n] = s3;
    }
}

// ---------------- h0 = x @ node_w + node_b  (f32 + bf16 copies) --------------
__global__ void node_encode_k(const float* __restrict__ x, const float* __restrict__ nw,
                              const float* __restrict__ nb, float* __restrict__ h,
                              unsigned short* __restrict__ h16) {
    int idx = blockIdx.x * 256 + threadIdx.x;
    if (idx >= N_NODES * HID) return;
    int n = idx >> 7, c = idx & 127;
    float acc = nb[c];
#pragma unroll
    for (int k = 0; k < NODE_IN; ++k) acc += x[n * NODE_IN + k] * nw[k * HID + c];
    h[idx] = acc;
    h16[idx] = f2b(acc);
}

// ---------------- gather (bf16 h): wave per node, exact grid -----------------
__global__ __launch_bounds__(256) void gather16_k(
    const int* __restrict__ row_ptr, const int* __restrict__ sorted_src,
    const float* __restrict__ y_l, const unsigned short* __restrict__ h16,
    unsigned int* __restrict__ gh16) {
    int lane = threadIdx.x & 63;
    int n = (blockIdx.x * 256 + threadIdx.x) >> 6;
    int ps = row_ptr[n], pe = row_ptr[n + 1];
    float a0 = 0.f, a1 = 0.f;
    int p = ps;
    for (; p + 3 < pe; p += 4) {
        int s0 = sorted_src[p], s1 = sorted_src[p + 1];
        int s2 = sorted_src[p + 2], s3 = sorted_src[p + 3];
        float y0 = y_l[p], y1 = y_l[p + 1], y2 = y_l[p + 2], y3 = y_l[p + 3];
        unsigned int v0 = *(const unsigned int*)(h16 + (size_t)s0 * HID + lane * 2);
        unsigned int v1 = *(const unsigned int*)(h16 + (size_t)s1 * HID + lane * 2);
        unsigned int v2 = *(const unsigned int*)(h16 + (size_t)s2 * HID + lane * 2);
        unsigned int v3 = *(const unsigned int*)(h16 + (size_t)s3 * HID + lane * 2);
        a0 += y0 * b2f((unsigned short)v0); a1 += y0 * b2f((unsigned short)(v0 >> 16));
        a0 += y1 * b2f((unsigned short)v1); a1 += y1 * b2f((unsigned short)(v1 >> 16));
        a0 += y2 * b2f((unsigned short)v2); a1 += y2 * b2f((unsigned short)(v2 >> 16));
        a0 += y3 * b2f((unsigned short)v3); a1 += y3 * b2f((unsigned short)(v3 >> 16));
    }
    for (; p < pe; ++p) {
        float y = y_l[p];
        unsigned int v = *(const unsigned int*)(h16 + (size_t)sorted_src[p] * HID + lane * 2);
        a0 += y * b2f((unsigned short)v);
        a1 += y * b2f((unsigned short)(v >> 16));
    }
    gh16[(size_t)n * 64 + lane] = ((unsigned int)f2b(a1) << 16) | f2b(a0);
}

// ---------------- MFMA GEMM + epilogue: 16 nodes/block, wave = 32 channels ---
__global__ __launch_bounds__(256) void mfma_ln_k(
    const unsigned short* __restrict__ gh16, const unsigned short* __restrict__ Wt16,
    const float* __restrict__ M_l, const float* __restrict__ cb_l,
    const float* __restrict__ agg8_l, const float* __restrict__ sy_l,
    const float* __restrict__ gm, const float* __restrict__ bt,
    const float* __restrict__ h_in, float* __restrict__ h_out,
    unsigned short* __restrict__ h16_out) {
    __shared__ float red[4][16][2];
    const int tid = threadIdx.x;
    const int w = tid >> 6, lane = tid & 63;
    const int g = lane >> 4, c = lane & 15;
    const int nbase = blockIdx.x * 16;
    const int cf0 = w * 2;

    bf16x8 afrag[4];
#pragma unroll
    for (int kc = 0; kc < 4; ++kc)
        afrag[kc] = *(const bf16x8*)(gh16 + (size_t)(nbase + c) * HID + kc * 32 + g * 8);

    f32x4 acc[2];
#pragma unroll
    for (int t = 0; t < 2; ++t) {
        acc[t] = (f32x4){0.f, 0.f, 0.f, 0.f};
        const unsigned short* wp = Wt16 + (size_t)((cf0 + t) * 16 + c) * HID + g * 8;
#pragma unroll
        for (int kc = 0; kc < 4; ++kc) {
            bf16x8 bfrag = *(const bf16x8*)(wp + kc * 32);
            acc[t] = __builtin_amdgcn_mfma_f32_16x16x32_bf16(afrag[kc], bfrag, acc[t], 0, 0, 0);
        }
    }

    float cbv[2], gav[2], bev[2], mv[2][8];
#pragma unroll
    for (int t = 0; t < 2; ++t) {
        int ch = (cf0 + t) * 16 + c;
        cbv[t] = cb_l[ch]; gav[t] = gm[ch]; bev[t] = bt[ch];
#pragma unroll
        for (int k = 0; k < 8; ++k) mv[t][k] = M_l[k * HID + ch];
    }
#pragma unroll
    for (int r = 0; r < 4; ++r) {
        int node = nbase + 4 * g + r;
        float sy = sy_l[node];
        float4 t0 = ((const float4*)agg8_l)[(size_t)node * 2];
        float4 t1 = ((const float4*)agg8_l)[(size_t)node * 2 + 1];
        float a8[8] = {t0.x, t0.y, t0.z, t0.w, t1.x, t1.y, t1.z, t1.w};
#pragma unroll
        for (int t = 0; t < 2; ++t) {
            float v = sy * cbv[t];
#pragma unroll
            for (int k = 0; k < 8; ++k) v += a8[k] * mv[t][k];
            acc[t][r] += v;
        }
    }

    float sx[4], sq[4];
#pragma unroll
    for (int r = 0; r < 4; ++r) {
        sx[r] = acc[0][r] + acc[1][r];
        sq[r] = acc[0][r] * acc[0][r] + acc[1][r] * acc[1][r];
    }
#pragma unroll
    for (int m = 1; m <= 8; m <<= 1) {
#pragma unroll
        for (int r = 0; r < 4; ++r) {
            sx[r] += __shfl_xor(sx[r], m, 64);
            sq[r] += __shfl_xor(sq[r], m, 64);
        }
    }
    if (c == 0) {
#pragma unroll
        for (int r = 0; r < 4; ++r) {
            red[w][4 * g + r][0] = sx[r];
            red[w][4 * g + r][1] = sq[r];
        }
    }
    __syncthreads();

#pragma unroll
    for (int r = 0; r < 4; ++r) {
        int row = 4 * g + r;
        float SX = red[0][row][0] + red[1][row][0] + red[2][row][0] + red[3][row][0];
        float SQ = red[0][row][1] + red[1][row][1] + red[2][row][1] + red[3][row][1];
        float mean = SX * (1.0f / HID);
        float var = SQ * (1.0f / HID) - mean * mean;
        float rstd = rsqrtf(var + LN_EPS);
        int node = nbase + row;
#pragma unroll
        for (int t = 0; t < 2; ++t) {
            int ch = (cf0 + t) * 16 + c;
            float d = acc[t][r] - mean;
            float o = h_in[(size_t)node * HID + ch] +
                      fmaxf(d * rstd * gav[t] + bev[t], 0.f);
            h_out[(size_t)node * HID + ch] = o;
            h16_out[(size_t)node * HID + ch] = f2b(o);
        }
    }
}

extern "C" void kernel_launch(void* const* d_in, const int* in_sizes, int n_in,
                              void* d_out, int out_size, void* d_ws, size_t ws_size,
                              hipStream_t stream) {
    const float* x         = (const float*)d_in[0];
    const void*  ei        = d_in[1];
    const float* edge_attr = (const float*)d_in[2];
    const float* node_w    = (const float*)d_in[3];
    const float* node_b    = (const float*)d_in[4];
    const float* edge_w    = (const float*)d_in[5];
    const float* edge_b    = (const float*)d_in[6];
    const float* lnode_w   = (const float*)d_in[7];
    const float* lnode_b   = (const float*)d_in[8];
    const float* ledge_w   = (const float*)d_in[9];
    const float* ledge_b   = (const float*)d_in[10];
    const float* adm_w     = (const float*)d_in[11];
    const float* adm_b     = (const float*)d_in[12];
    const float* gamma     = (const float*)d_in[13];
    const float* beta      = (const float*)d_in[14];
    float* h = (float*)d_out;

    char* wp = (char*)d_ws;
    auto alloc = [&](size_t bytes) -> void* {
        void* p = (void*)wp;
        wp += (bytes + 255) & ~(size_t)255;
        return p;
    };
    int*            flag       = (int*)alloc(256);
    int*            cursor     = (int*)alloc(sizeof(int) * N_NODES);
    int*            row_ptr    = (int*)alloc(sizeof(int) * (N_NODES + 1));
    int*            partials   = (int*)alloc(sizeof(int) * (SCAN_BLOCKS + 1));
    int*            sorted_src = (int*)alloc(sizeof(int) * N_EDGES);
    int*            sorted_eid = (int*)alloc(sizeof(int) * N_EDGES);
    float*          y_sorted   = (float*)alloc(sizeof(float) * NLAYERS * N_EDGES);
    float*          agg8       = (float*)alloc(sizeof(float) * NLAYERS * N_NODES * 8);
    float*          sy_arr     = (float*)alloc(sizeof(float) * NLAYERS * N_NODES);
    float*          Mw         = (float*)alloc(sizeof(float) * NLAYERS * 8 * HID);
    float*          cbw        = (float*)alloc(sizeof(float) * NLAYERS * HID);
    float*          vw         = (float*)alloc(sizeof(float) * NLAYERS * 8);
    float*          cgate      = (float*)alloc(sizeof(float) * NLAYERS);
    float*          hbuf       = (float*)alloc(sizeof(float) * (size_t)N_NODES * HID);
    unsigned short* h16        = (unsigned short*)alloc(sizeof(short) * (size_t)N_NODES * HID);
    unsigned short* gh16       = (unsigned short*)alloc(sizeof(short) * (size_t)N_NODES * HID);
    unsigned short* Wt16       = (unsigned short*)alloc(sizeof(short) * NLAYERS * HID * HID);
    (void)ws_size; (void)in_sizes; (void)n_in; (void)out_size;

    hipMemsetAsync(cursor, 0, sizeof(int) * N_NODES, stream);
    detect_i64<<<1, 256, 0, stream>>>((const int*)ei, flag);
    hist_k<<<(N_EDGES + 255) / 256, 256, 0, stream>>>(ei, flag, cursor);
    scan1_k<<<SCAN_BLOCKS, 256, 0, stream>>>(cursor, row_ptr, partials);
    scan2_k<<<1, 256, 0, stream>>>(partials);
    scan3_k<<<SCAN_BLOCKS, 256, 0, stream>>>(row_ptr, cursor, partials);
    place_k<<<(N_EDGES + 255) / 256, 256, 0, stream>>>(ei, flag, cursor, sorted_src, sorted_eid);
    precompute_k<<<19, 256, 0, stream>>>(edge_w, edge_b, ledge_w, ledge_b, lnode_b,
                                         adm_w, adm_b, Mw, cbw, vw, cgate);
    convertw_k<<<(NLAYERS * HID * HID + 255) / 256, 256, 0, stream>>>(lnode_w, Wt16);
    node_stats_k<<<N_NODES / 4, 256, 0, stream>>>(row_ptr, sorted_eid, edge_attr,
                                                  vw, cgate, agg8, sy_arr, y_sorted);
    node_encode_k<<<(N_NODES * HID + 255) / 256, 256, 0, stream>>>(x, node_w, node_b, h, h16);

    float* hin = h;
    float* hout = hbuf;
    for (int l = 0; l < NLAYERS; ++l) {
        gather16_k<<<N_NODES / 4, 256, 0, stream>>>(
            row_ptr, sorted_src, y_sorted + (size_t)l * N_EDGES, h16, (unsigned int*)gh16);
        mfma_ln_k<<<N_NODES / 16, 256, 0, stream>>>(
            gh16, Wt16 + (size_t)l * HID * HID,
            Mw + (size_t)l * 8 * HID, cbw + (size_t)l * HID,
            agg8 + (size_t)l * N_NODES * 8, sy_arr + (size_t)l * N_NODES,
            gamma + (size_t)l * HID, beta + (size_t)l * HID,
            hin, hout, h16);
        float* t = hin; hin = hout; hout = t;
    }
    // NLAYERS even -> final f32 result lands in d_out
}

// Round 8
// 376.807 us; speedup vs baseline: 3.5420x; 1.0371x over previous
//
#include <hip/hip_runtime.h>
#include <math.h>

#define N_NODES 50000
#define N_EDGES 600000
#define HID 128
#define NLAYERS 4
#define NODE_IN 16
#define EDGE_IN 8
#define LN_EPS 1e-5f
#define SCAN_BLOCKS ((N_NODES + 255) / 256)

typedef short bf16x8 __attribute__((ext_vector_type(8)));
typedef float f32x4 __attribute__((ext_vector_type(4)));

__device__ __forceinline__ float b2f(unsigned short u) {
    union { unsigned int i; float f; } v; v.i = ((unsigned int)u) << 16; return v.f;
}
__device__ __forceinline__ unsigned short f2b(float x) {
    union { float f; unsigned int i; } v; v.f = x;
    unsigned int b = v.i + 0x7FFFu + ((v.i >> 16) & 1u);
    return (unsigned short)(b >> 16);
}

// ---------------- edge_index dtype detection (int32 vs int64) ----------------
__global__ void detect_i64(const int* ei, int* flag) {
    __shared__ int nz;
    if (threadIdx.x == 0) nz = 0;
    __syncthreads();
    int acc = 0;
    for (int i = threadIdx.x; i < 1024; i += blockDim.x)
        if (ei[2 * i + 1] != 0) acc = 1;
    if (acc) atomicOr(&nz, 1);
    __syncthreads();
    if (threadIdx.x == 0) *flag = (nz == 0) ? 1 : 0;
}

__device__ __forceinline__ int edge_src(const void* ei, int f, int e) {
    if (f) return (int)((const long long*)ei)[e];
    return ((const int*)ei)[e];
}
__device__ __forceinline__ int edge_dst(const void* ei, int f, int e) {
    if (f) return (int)((const long long*)ei)[N_EDGES + e];
    return ((const int*)ei)[N_EDGES + e];
}

// ---------------- CSR build ----------------
__global__ void hist_k(const void* ei, const int* flag, int* cursor) {
    int e = blockIdx.x * blockDim.x + threadIdx.x;
    if (e >= N_EDGES) return;
    int f = *flag;
    atomicAdd(&cursor[edge_dst(ei, f, e)], 1);
}

__global__ void scan1_k(const int* __restrict__ cursor, int* __restrict__ locex,
                        int* __restrict__ partials) {
    __shared__ int sd[256];
    int t = threadIdx.x, i = blockIdx.x * 256 + t;
    int v = (i < N_NODES) ? cursor[i] : 0;
    sd[t] = v;
    __syncthreads();
    for (int off = 1; off < 256; off <<= 1) {
        int x = (t >= off) ? sd[t - off] : 0;
        __syncthreads();
        sd[t] += x;
        __syncthreads();
    }
    if (i < N_NODES) locex[i] = sd[t] - v;
    if (t == 255) partials[blockIdx.x] = sd[255];
}

__global__ void scan2_k(int* partials) {
    __shared__ int sd[256];
    int t = threadIdx.x;
    int v = (t < SCAN_BLOCKS) ? partials[t] : 0;
    sd[t] = v;
    __syncthreads();
    for (int off = 1; off < 256; off <<= 1) {
        int x = (t >= off) ? sd[t - off] : 0;
        __syncthreads();
        sd[t] += x;
        __syncthreads();
    }
    if (t < SCAN_BLOCKS) partials[t] = sd[t] - v;
    if (t == 255) partials[SCAN_BLOCKS] = sd[255];
}

__global__ void scan3_k(int* __restrict__ row_ptr, int* __restrict__ cursor,
                        const int* __restrict__ partials) {
    int i = blockIdx.x * 256 + threadIdx.x;
    if (i < N_NODES) {
        int r = row_ptr[i] + partials[blockIdx.x];
        row_ptr[i] = r;
        cursor[i] = r;
    }
    if (i == N_NODES) row_ptr[N_NODES] = partials[SCAN_BLOCKS];
}

__global__ void place_k(const void* ei, const int* flag, int* cursor,
                        int* sorted_src, int* sorted_eid) {
    int e = blockIdx.x * blockDim.x + threadIdx.x;
    if (e >= N_EDGES) return;
    int f = *flag;
    int s = edge_src(ei, f, e);
    int d = edge_dst(ei, f, e);
    int pos = atomicAdd(&cursor[d], 1);
    sorted_src[pos] = s;
    sorted_eid[pos] = e;
}

// ---------------- weight precompute (f32 epilogue constants) ----------------
__global__ void precompute_k(const float* __restrict__ edge_w, const float* __restrict__ edge_b,
                             const float* __restrict__ ledge_w, const float* __restrict__ ledge_b,
                             const float* __restrict__ lnode_b,
                             const float* __restrict__ adm_w, const float* __restrict__ adm_b,
                             float* __restrict__ M, float* __restrict__ cb,
                             float* __restrict__ v, float* __restrict__ cgate) {
    int t = blockIdx.x * 256 + threadIdx.x;
    if (t < 4096) {
        int l = t >> 10, k = (t >> 7) & 7, ch = t & 127;
        const float* lw = ledge_w + (size_t)l * HID * HID;
        float a = 0.f;
        for (int j = 0; j < HID; ++j) a += edge_w[k * HID + j] * lw[j * HID + ch];
        M[t] = a;
    } else if (t < 4608) {
        int u = t - 4096;
        int l = u >> 7, ch = u & 127;
        const float* lw = ledge_w + (size_t)l * HID * HID;
        float a = ledge_b[l * HID + ch] + lnode_b[l * HID + ch];
        for (int j = 0; j < HID; ++j) a += edge_b[j] * lw[j * HID + ch];
        cb[u] = a;
    } else if (t < 4640) {
        int u = t - 4608;
        int l = u >> 3, k = u & 7;
        float a = 0.f;
        for (int j = 0; j < HID; ++j) a += edge_w[k * HID + j] * adm_w[l * HID + j];
        v[u] = a;
    } else if (t < 4644) {
        int l = t - 4640;
        float a = adm_b[l];
        for (int j = 0; j < HID; ++j) a += edge_b[j] * adm_w[l * HID + j];
        cgate[l] = a;
    }
}

// ---- W^T bf16: Wt16[l][n][k] = bf16(lnode_w[l][k][n]) (B-operand, k-contig) --
__global__ void convertw_k(const float* __restrict__ lnode_w, unsigned short* __restrict__ Wt16) {
    int idx = blockIdx.x * 256 + threadIdx.x;
    if (idx >= NLAYERS * HID * HID) return;
    int l = idx >> 14, r = idx & 16383, n = r >> 7, k = r & 127;
    Wt16[idx] = f2b(lnode_w[(size_t)l * HID * HID + k * HID + n]);
}

// ---------------- reorder + gates: thread per sorted position ----------------
// Coalesced eid read; one random 32B edge_attr gather; in-thread gate dots +
// fast sigmoid; fully coalesced writes of ea_sorted and 4 y streams.
__global__ __launch_bounds__(256) void reorder_k(
    const int* __restrict__ sorted_eid, const float* __restrict__ edge_attr,
    const float* __restrict__ vw, const float* __restrict__ cgate,
    float* __restrict__ ea_sorted, float* __restrict__ y_sorted) {
    __shared__ float sv[36];
    if (threadIdx.x < 32) sv[threadIdx.x] = vw[threadIdx.x];
    else if (threadIdx.x < 36) sv[threadIdx.x] = cgate[threadIdx.x - 32];
    __syncthreads();
    int p = blockIdx.x * 256 + threadIdx.x;
    if (p >= N_EDGES) return;
    int eid = sorted_eid[p];
    float4 a0 = ((const float4*)edge_attr)[(size_t)eid * 2];
    float4 a1 = ((const float4*)edge_attr)[(size_t)eid * 2 + 1];
    ((float4*)ea_sorted)[(size_t)p * 2] = a0;
    ((float4*)ea_sorted)[(size_t)p * 2 + 1] = a1;
#pragma unroll
    for (int l = 0; l < NLAYERS; ++l) {
        const float* vl = &sv[l * 8];
        float t = sv[32 + l];
        t += a0.x * vl[0] + a0.y * vl[1] + a0.z * vl[2] + a0.w * vl[3];
        t += a1.x * vl[4] + a1.y * vl[5] + a1.z * vl[6] + a1.w * vl[7];
        y_sorted[(size_t)l * N_EDGES + p] = 1.0f / (1.0f + __expf(-t));
    }
}

// ---------------- per-node edge stats: pure streaming, wave per node ---------
__global__ __launch_bounds__(256) void node_stats_k(
    const int* __restrict__ row_ptr, const float* __restrict__ ea_sorted,
    const float* __restrict__ y_sorted,
    float* __restrict__ agg8, float* __restrict__ sy_arr) {
    int lane = threadIdx.x & 63;
    int n = (blockIdx.x * 256 + threadIdx.x) >> 6;
    int es = lane >> 3, k = lane & 7;
    int ps = row_ptr[n], pe = row_ptr[n + 1];
    float a0 = 0.f, a1 = 0.f, a2 = 0.f, a3 = 0.f;
    float s0 = 0.f, s1 = 0.f, s2 = 0.f, s3 = 0.f;
    for (int p = ps + es; p < pe; p += 8) {
        float ea = ea_sorted[(size_t)p * EDGE_IN + k];
        float y0 = y_sorted[(size_t)0 * N_EDGES + p];
        float y1 = y_sorted[(size_t)1 * N_EDGES + p];
        float y2 = y_sorted[(size_t)2 * N_EDGES + p];
        float y3 = y_sorted[(size_t)3 * N_EDGES + p];
        a0 += y0 * ea; a1 += y1 * ea; a2 += y2 * ea; a3 += y3 * ea;
        s0 += y0; s1 += y1; s2 += y2; s3 += y3;
    }
#pragma unroll
    for (int m = 8; m <= 32; m <<= 1) {
        a0 += __shfl_xor(a0, m, 64); a1 += __shfl_xor(a1, m, 64);
        a2 += __shfl_xor(a2, m, 64); a3 += __shfl_xor(a3, m, 64);
        s0 += __shfl_xor(s0, m, 64); s1 += __shfl_xor(s1, m, 64);
        s2 += __shfl_xor(s2, m, 64); s3 += __shfl_xor(s3, m, 64);
    }
    if (lane < 8) {
        agg8[((size_t)0 * N_NODES + n) * 8 + k] = a0;
        agg8[((size_t)1 * N_NODES + n) * 8 + k] = a1;
        agg8[((size_t)2 * N_NODES + n) * 8 + k] = a2;
        agg8[((size_t)3 * N_NODES + n) * 8 + k] = a3;
    }
    if (lane == 0) {
        sy_arr[(size_t)0 * N_NODES + n] = s0;
        sy_arr[(size_t)1 * N_NODES + n] = s1;
        sy_arr[(size_t)2 * N_NODES + n] = s2;
        sy_arr[(size_t)3 * N_NODES + n] = s3;
    }
}

// ---------------- h0 = x @ node_w + node_b  (f32 + bf16 copies) --------------
__global__ void node_encode_k(const float* __restrict__ x, const float* __restrict__ nw,
                              const float* __restrict__ nb, float* __restrict__ h,
                              unsigned short* __restrict__ h16) {
    int idx = blockIdx.x * 256 + threadIdx.x;
    if (idx >= N_NODES * HID) return;
    int n = idx >> 7, c = idx & 127;
    float acc = nb[c];
#pragma unroll
    for (int k = 0; k < NODE_IN; ++k) acc += x[n * NODE_IN + k] * nw[k * HID + c];
    h[idx] = acc;
    h16[idx] = f2b(acc);
}

// ---------------- gather (bf16 h): wave per node, 8-deep unroll --------------
__global__ __launch_bounds__(256) void gather16_k(
    const int* __restrict__ row_ptr, const int* __restrict__ sorted_src,
    const float* __restrict__ y_l, const unsigned short* __restrict__ h16,
    unsigned int* __restrict__ gh16) {
    int lane = threadIdx.x & 63;
    int n = (blockIdx.x * 256 + threadIdx.x) >> 6;
    int ps = row_ptr[n], pe = row_ptr[n + 1];
    float a0 = 0.f, a1 = 0.f;
    int p = ps;
    for (; p + 7 < pe; p += 8) {
        int s[8];
        float y[8];
        unsigned int v[8];
#pragma unroll
        for (int i = 0; i < 8; ++i) { s[i] = sorted_src[p + i]; y[i] = y_l[p + i]; }
#pragma unroll
        for (int i = 0; i < 8; ++i)
            v[i] = *(const unsigned int*)(h16 + (size_t)s[i] * HID + lane * 2);
#pragma unroll
        for (int i = 0; i < 8; ++i) {
            a0 += y[i] * b2f((unsigned short)v[i]);
            a1 += y[i] * b2f((unsigned short)(v[i] >> 16));
        }
    }
    for (; p + 3 < pe; p += 4) {
        int s[4];
        float y[4];
        unsigned int v[4];
#pragma unroll
        for (int i = 0; i < 4; ++i) { s[i] = sorted_src[p + i]; y[i] = y_l[p + i]; }
#pragma unroll
        for (int i = 0; i < 4; ++i)
            v[i] = *(const unsigned int*)(h16 + (size_t)s[i] * HID + lane * 2);
#pragma unroll
        for (int i = 0; i < 4; ++i) {
            a0 += y[i] * b2f((unsigned short)v[i]);
            a1 += y[i] * b2f((unsigned short)(v[i] >> 16));
        }
    }
    for (; p < pe; ++p) {
        float y = y_l[p];
        unsigned int v = *(const unsigned int*)(h16 + (size_t)sorted_src[p] * HID + lane * 2);
        a0 += y * b2f((unsigned short)v);
        a1 += y * b2f((unsigned short)(v >> 16));
    }
    gh16[(size_t)n * 64 + lane] = ((unsigned int)f2b(a1) << 16) | f2b(a0);
}

// ---------------- MFMA GEMM + epilogue: 16 nodes/block, wave = 32 channels ---
__global__ __launch_bounds__(256) void mfma_ln_k(
    const unsigned short* __restrict__ gh16, const unsigned short* __restrict__ Wt16,
    const float* __restrict__ M_l, const float* __restrict__ cb_l,
    const float* __restrict__ agg8_l, const float* __restrict__ sy_l,
    const float* __restrict__ gm, const float* __restrict__ bt,
    const float* __restrict__ h_in, float* __restrict__ h_out,
    unsigned short* __restrict__ h16_out) {
    __shared__ float red[4][16][2];
    const int tid = threadIdx.x;
    const int w = tid >> 6, lane = tid & 63;
    const int g = lane >> 4, c = lane & 15;
    const int nbase = blockIdx.x * 16;
    const int cf0 = w * 2;

    bf16x8 afrag[4];
#pragma unroll
    for (int kc = 0; kc < 4; ++kc)
        afrag[kc] = *(const bf16x8*)(gh16 + (size_t)(nbase + c) * HID + kc * 32 + g * 8);

    f32x4 acc[2];
#pragma unroll
    for (int t = 0; t < 2; ++t) {
        acc[t] = (f32x4){0.f, 0.f, 0.f, 0.f};
        const unsigned short* wp = Wt16 + (size_t)((cf0 + t) * 16 + c) * HID + g * 8;
#pragma unroll
        for (int kc = 0; kc < 4; ++kc) {
            bf16x8 bfrag = *(const bf16x8*)(wp + kc * 32);
            acc[t] = __builtin_amdgcn_mfma_f32_16x16x32_bf16(afrag[kc], bfrag, acc[t], 0, 0, 0);
        }
    }

    float cbv[2], gav[2], bev[2], mv[2][8];
#pragma unroll
    for (int t = 0; t < 2; ++t) {
        int ch = (cf0 + t) * 16 + c;
        cbv[t] = cb_l[ch]; gav[t] = gm[ch]; bev[t] = bt[ch];
#pragma unroll
        for (int k = 0; k < 8; ++k) mv[t][k] = M_l[k * HID + ch];
    }
#pragma unroll
    for (int r = 0; r < 4; ++r) {
        int node = nbase + 4 * g + r;
        float sy = sy_l[node];
        float4 t0 = ((const float4*)agg8_l)[(size_t)node * 2];
        float4 t1 = ((const float4*)agg8_l)[(size_t)node * 2 + 1];
        float a8[8] = {t0.x, t0.y, t0.z, t0.w, t1.x, t1.y, t1.z, t1.w};
#pragma unroll
        for (int t = 0; t < 2; ++t) {
            float v = sy * cbv[t];
#pragma unroll
            for (int k = 0; k < 8; ++k) v += a8[k] * mv[t][k];
            acc[t][r] += v;
        }
    }

    float sx[4], sq[4];
#pragma unroll
    for (int r = 0; r < 4; ++r) {
        sx[r] = acc[0][r] + acc[1][r];
        sq[r] = acc[0][r] * acc[0][r] + acc[1][r] * acc[1][r];
    }
#pragma unroll
    for (int m = 1; m <= 8; m <<= 1) {
#pragma unroll
        for (int r = 0; r < 4; ++r) {
            sx[r] += __shfl_xor(sx[r], m, 64);
            sq[r] += __shfl_xor(sq[r], m, 64);
        }
    }
    if (c == 0) {
#pragma unroll
        for (int r = 0; r < 4; ++r) {
            red[w][4 * g + r][0] = sx[r];
            red[w][4 * g + r][1] = sq[r];
        }
    }
    __syncthreads();

#pragma unroll
    for (int r = 0; r < 4; ++r) {
        int row = 4 * g + r;
        float SX = red[0][row][0] + red[1][row][0] + red[2][row][0] + red[3][row][0];
        float SQ = red[0][row][1] + red[1][row][1] + red[2][row][1] + red[3][row][1];
        float mean = SX * (1.0f / HID);
        float var = SQ * (1.0f / HID) - mean * mean;
        float rstd = rsqrtf(var + LN_EPS);
        int node = nbase + row;
#pragma unroll
        for (int t = 0; t < 2; ++t) {
            int ch = (cf0 + t) * 16 + c;
            float d = acc[t][r] - mean;
            float o = h_in[(size_t)node * HID + ch] +
                      fmaxf(d * rstd * gav[t] + bev[t], 0.f);
            h_out[(size_t)node * HID + ch] = o;
            h16_out[(size_t)node * HID + ch] = f2b(o);
        }
    }
}

extern "C" void kernel_launch(void* const* d_in, const int* in_sizes, int n_in,
                              void* d_out, int out_size, void* d_ws, size_t ws_size,
                              hipStream_t stream) {
    const float* x         = (const float*)d_in[0];
    const void*  ei        = d_in[1];
    const float* edge_attr = (const float*)d_in[2];
    const float* node_w    = (const float*)d_in[3];
    const float* node_b    = (const float*)d_in[4];
    const float* edge_w    = (const float*)d_in[5];
    const float* edge_b    = (const float*)d_in[6];
    const float* lnode_w   = (const float*)d_in[7];
    const float* lnode_b   = (const float*)d_in[8];
    const float* ledge_w   = (const float*)d_in[9];
    const float* ledge_b   = (const float*)d_in[10];
    const float* adm_w     = (const float*)d_in[11];
    const float* adm_b     = (const float*)d_in[12];
    const float* gamma     = (const float*)d_in[13];
    const float* beta      = (const float*)d_in[14];
    float* h = (float*)d_out;

    char* wp = (char*)d_ws;
    auto alloc = [&](size_t bytes) -> void* {
        void* p = (void*)wp;
        wp += (bytes + 255) & ~(size_t)255;
        return p;
    };
    int*            flag       = (int*)alloc(256);
    int*            cursor     = (int*)alloc(sizeof(int) * N_NODES);
    int*            row_ptr    = (int*)alloc(sizeof(int) * (N_NODES + 1));
    int*            partials   = (int*)alloc(sizeof(int) * (SCAN_BLOCKS + 1));
    int*            sorted_src = (int*)alloc(sizeof(int) * N_EDGES);
    int*            sorted_eid = (int*)alloc(sizeof(int) * N_EDGES);
    float*          ea_sorted  = (float*)alloc(sizeof(float) * (size_t)N_EDGES * EDGE_IN);
    float*          y_sorted   = (float*)alloc(sizeof(float) * NLAYERS * N_EDGES);
    float*          agg8       = (float*)alloc(sizeof(float) * NLAYERS * N_NODES * 8);
    float*          sy_arr     = (float*)alloc(sizeof(float) * NLAYERS * N_NODES);
    float*          Mw         = (float*)alloc(sizeof(float) * NLAYERS * 8 * HID);
    float*          cbw        = (float*)alloc(sizeof(float) * NLAYERS * HID);
    float*          vw         = (float*)alloc(sizeof(float) * NLAYERS * 8);
    float*          cgate      = (float*)alloc(sizeof(float) * NLAYERS);
    float*          hbuf       = (float*)alloc(sizeof(float) * (size_t)N_NODES * HID);
    unsigned short* h16        = (unsigned short*)alloc(sizeof(short) * (size_t)N_NODES * HID);
    unsigned short* gh16       = (unsigned short*)alloc(sizeof(short) * (size_t)N_NODES * HID);
    unsigned short* Wt16       = (unsigned short*)alloc(sizeof(short) * NLAYERS * HID * HID);
    (void)ws_size; (void)in_sizes; (void)n_in; (void)out_size;

    hipMemsetAsync(cursor, 0, sizeof(int) * N_NODES, stream);
    detect_i64<<<1, 256, 0, stream>>>((const int*)ei, flag);
    hist_k<<<(N_EDGES + 255) / 256, 256, 0, stream>>>(ei, flag, cursor);
    scan1_k<<<SCAN_BLOCKS, 256, 0, stream>>>(cursor, row_ptr, partials);
    scan2_k<<<1, 256, 0, stream>>>(partials);
    scan3_k<<<SCAN_BLOCKS, 256, 0, stream>>>(row_ptr, cursor, partials);
    place_k<<<(N_EDGES + 255) / 256, 256, 0, stream>>>(ei, flag, cursor, sorted_src, sorted_eid);
    precompute_k<<<19, 256, 0, stream>>>(edge_w, edge_b, ledge_w, ledge_b, lnode_b,
                                         adm_w, adm_b, Mw, cbw, vw, cgate);
    convertw_k<<<(NLAYERS * HID * HID + 255) / 256, 256, 0, stream>>>(lnode_w, Wt16);
    reorder_k<<<(N_EDGES + 255) / 256, 256, 0, stream>>>(sorted_eid, edge_attr,
                                                         vw, cgate, ea_sorted, y_sorted);
    node_stats_k<<<N_NODES / 4, 256, 0, stream>>>(row_ptr, ea_sorted, y_sorted,
                                                  agg8, sy_arr);
    node_encode_k<<<(N_NODES * HID + 255) / 256, 256, 0, stream>>>(x, node_w, node_b, h, h16);

    float* hin = h;
    float* hout = hbuf;
    for (int l = 0; l < NLAYERS; ++l) {
        gather16_k<<<N_NODES / 4, 256, 0, stream>>>(
            row_ptr, sorted_src, y_sorted + (size_t)l * N_EDGES, h16, (unsigned int*)gh16);
        mfma_ln_k<<<N_NODES / 16, 256, 0, stream>>>(
            gh16, Wt16 + (size_t)l * HID * HID,
            Mw + (size_t)l * 8 * HID, cbw + (size_t)l * HID,
            agg8 + (size_t)l * N_NODES * 8, sy_arr + (size_t)l * N_NODES,
            gamma + (size_t)l * HID, beta + (size_t)l * HID,
            hin, hout, h16);
        float* t = hin; hin = hout; hout = t;
    }
    // NLAYERS even -> final f32 result lands in d_out
}